// Round 11
// baseline (161.914 us; speedup 1.0000x reference)
//
#include <hip/hip_runtime.h>

// B = IN = OUT = 512; T from out_size.
// v_t = P_t @ x^T [OUT,B]; G = x@x^T [B,B]
//   u = k*(M*e^{-t} + a*v);  h = (u>0);  s = (u>0.2)
//   v' = d*v + e*(h@G + bt*colsum(G))
// Round-11:
//  snn: 32-wide batched delta apply (4 LDS uint4 -> 32 independent G loads ->
//       one waitcnt -> 32 select-adds), 2 barriers transient / 1 frozen.
//  gemm: split-K x2, grid 512 (exactly 2 blocks/CU), dual M/V0 blocks share
//       the B tile (2 B LDS per fma). M/V0 partials combined in snn init
//       (round-7-validated), G partials by a tiny combine kernel.

#define NN 512

// ---- Split-K GEMMs (NT), grid 512:
//  bid<256:  dual: kh=bid>>7, tile=bid&127: M_kh = W·x^T, V0_kh = P0·x^T (raw)
//  bid>=256: G:    kh,tile likewise:        G_kh = x·x^T (raw)
// 32x64 tile, 256 thr, 2x4 micro, KC=32, K-half = 256, reg double-buffer.
__global__ __launch_bounds__(256) void gemm_dual_split_kernel(
    const float* __restrict__ x, const float* __restrict__ W,
    const float* __restrict__ P0,
    float* __restrict__ M1, float* __restrict__ M2,
    float* __restrict__ V01, float* __restrict__ V02,
    float* __restrict__ G1, float* __restrict__ G2)
{
    const int tid = threadIdx.x;
    const int bid = blockIdx.x;
    const bool dual = bid < 256;
    const int b2 = dual ? bid : bid - 256;
    const int kh = b2 >> 7;
    const int tl = b2 & 127;
    const int rb = (tl >> 3) << 5;       // 16 row-tiles of 32
    const int cb = (tl & 7) << 6;        // 8 col-tiles of 64
    const int kbase = kh << 8;

    const float* A1 = (dual ? W : x) + (size_t)rb * NN;
    const float* A2 = P0 + (size_t)rb * NN;      // read only when dual
    float* D1 = dual ? (kh ? M2 : M1) : (kh ? G2 : G1);
    float* D2 = kh ? V02 : V01;

    const int tx = tid & 15;             // cols 4tx..4tx+3
    const int ty = tid >> 4;             // rows 2ty, 2ty+1

    __shared__ float A1t[32][36];
    __shared__ float A2t[32][36];
    __shared__ float Bt[32][68];

    const int ar = tid >> 3;             // 0..31
    const int ak = (tid & 7) << 2;       // 0,4,...,28
    const int br = tid >> 2;             // 0..63
    const int bk = (tid & 3) << 3;       // 0,8,16,24

    float acc1[2][4] = {{0.f, 0.f, 0.f, 0.f}, {0.f, 0.f, 0.f, 0.f}};
    float acc2[2][4] = {{0.f, 0.f, 0.f, 0.f}, {0.f, 0.f, 0.f, 0.f}};

    float4 av4 = *(const float4*)(A1 + (size_t)ar * NN + kbase + ak);
    float4 bv4a = *(const float4*)(x + (size_t)(cb + br) * NN + kbase + bk);
    float4 bv4b = *(const float4*)(x + (size_t)(cb + br) * NN + kbase + bk + 4);
    float4 cv4 = make_float4(0.f, 0.f, 0.f, 0.f);
    if (dual) cv4 = *(const float4*)(A2 + (size_t)ar * NN + kbase + ak);

    for (int c = 0; c < 8; ++c) {
        __syncthreads();
        A1t[ak + 0][ar] = av4.x; A1t[ak + 1][ar] = av4.y;
        A1t[ak + 2][ar] = av4.z; A1t[ak + 3][ar] = av4.w;
        Bt[bk + 0][br] = bv4a.x; Bt[bk + 1][br] = bv4a.y;
        Bt[bk + 2][br] = bv4a.z; Bt[bk + 3][br] = bv4a.w;
        Bt[bk + 4][br] = bv4b.x; Bt[bk + 5][br] = bv4b.y;
        Bt[bk + 6][br] = bv4b.z; Bt[bk + 7][br] = bv4b.w;
        if (dual) {
            A2t[ak + 0][ar] = cv4.x; A2t[ak + 1][ar] = cv4.y;
            A2t[ak + 2][ar] = cv4.z; A2t[ak + 3][ar] = cv4.w;
        }
        __syncthreads();

        if (c < 7) {
            const int k0 = kbase + ((c + 1) << 5);
            av4 = *(const float4*)(A1 + (size_t)ar * NN + k0 + ak);
            bv4a = *(const float4*)(x + (size_t)(cb + br) * NN + k0 + bk);
            bv4b = *(const float4*)(x + (size_t)(cb + br) * NN + k0 + bk + 4);
            if (dual) cv4 = *(const float4*)(A2 + (size_t)ar * NN + k0 + ak);
        }

#pragma unroll
        for (int k = 0; k < 32; ++k) {
            const float2 av = *(const float2*)&A1t[k][2 * ty];
            const float4 bv = *(const float4*)&Bt[k][4 * tx];
            acc1[0][0] = fmaf(av.x, bv.x, acc1[0][0]);
            acc1[0][1] = fmaf(av.x, bv.y, acc1[0][1]);
            acc1[0][2] = fmaf(av.x, bv.z, acc1[0][2]);
            acc1[0][3] = fmaf(av.x, bv.w, acc1[0][3]);
            acc1[1][0] = fmaf(av.y, bv.x, acc1[1][0]);
            acc1[1][1] = fmaf(av.y, bv.y, acc1[1][1]);
            acc1[1][2] = fmaf(av.y, bv.z, acc1[1][2]);
            acc1[1][3] = fmaf(av.y, bv.w, acc1[1][3]);
            if (dual) {
                const float2 cv = *(const float2*)&A2t[k][2 * ty];
                acc2[0][0] = fmaf(cv.x, bv.x, acc2[0][0]);
                acc2[0][1] = fmaf(cv.x, bv.y, acc2[0][1]);
                acc2[0][2] = fmaf(cv.x, bv.z, acc2[0][2]);
                acc2[0][3] = fmaf(cv.x, bv.w, acc2[0][3]);
                acc2[1][0] = fmaf(cv.y, bv.x, acc2[1][0]);
                acc2[1][1] = fmaf(cv.y, bv.y, acc2[1][1]);
                acc2[1][2] = fmaf(cv.y, bv.z, acc2[1][2]);
                acc2[1][3] = fmaf(cv.y, bv.w, acc2[1][3]);
            }
        }
    }

#pragma unroll
    for (int i = 0; i < 2; ++i) {
        const int r = rb + 2 * ty + i;
        *(float4*)(D1 + (size_t)r * NN + cb + 4 * tx) =
            make_float4(acc1[i][0], acc1[i][1], acc1[i][2], acc1[i][3]);
        if (dual) {
            *(float4*)(D2 + (size_t)r * NN + cb + 4 * tx) =
                make_float4(acc2[i][0], acc2[i][1], acc2[i][2], acc2[i][3]);
        }
    }
}

// ---- combine: G = G1 + G2, grid 256 x 256 thr, float4 each.
__global__ __launch_bounds__(256) void combine_kernel(
    const float4* __restrict__ G1, const float4* __restrict__ G2,
    float4* __restrict__ G)
{
    const int i = blockIdx.x * 256 + threadIdx.x;
    const float4 a = G1[i];
    const float4 b = G2[i];
    G[i] = make_float4(a.x + b.x, a.y + b.y, a.z + b.z, a.w + b.w);
}

// ---- colsum: 8 blocks x 256 thr
__global__ __launch_bounds__(256) void colsum_kernel(
    const float* __restrict__ G, float* __restrict__ gs)
{
    __shared__ float red[4][64];
    const int tid = threadIdx.x;
    const int c = (blockIdx.x << 6) + (tid & 63);
    const int g = tid >> 6;
    float s = 0.f;
    for (int bp = 128 * g; bp < 128 * g + 128; ++bp) s += G[(size_t)bp * NN + c];
    if (g > 0) red[g][tid & 63] = s;
    __syncthreads();
    if (g == 0) gs[c] = ((s + red[1][tid & 63]) + red[2][tid & 63]) + red[3][tid & 63];
}

// ---- Main recurrence: 512 blocks x 512 threads. Thread owns col c = tid.
// Frozen: 1 barrier + 8B flag. Transient: compact list build (2nd barrier),
// then 32-wide apply: 4 uint4 LDS reads -> 32 independent G loads -> one
// waitcnt -> 32 exact select-adds (tail adds 0.0f).
__global__ __launch_bounds__(512) void snn_bits5_kernel(
    const float* __restrict__ M1, const float* __restrict__ M2,
    const float* __restrict__ bias, const float* __restrict__ G,
    const float* __restrict__ V01, const float* __restrict__ V02,
    const float* __restrict__ gs, const float* __restrict__ alpha,
    const float* __restrict__ eta, const float* __restrict__ beta,
    unsigned* __restrict__ sp, int T)
{
    const int tid = threadIdx.x;
    const int w = tid >> 6;
    const int lane = tid & 63;
    const int r = blockIdx.x;

    __shared__ unsigned long long lmask[2][8];
    __shared__ unsigned long long lflag[2];
    __shared__ unsigned long long omask[8];
    __shared__ unsigned short list[544] __attribute__((aligned(16)));

    const float a = alpha[0], e = eta[0], bt = beta[0];
    const float kk = 0.2f;
    const float dd = 0.36787944117144233f;   // exp(-1)
    const float Vth = 0.2f;

    const size_t rc = (size_t)r * NN + tid;
    const float m = fmaxf(M1[rc] + M2[rc] + bias[r], 0.f);
    float v = V01[rc] + V02[rc];
    const float cg = e * bt * gs[tid];
    const float* Gc = G + tid;

    if (tid < 8) omask[tid] = 0ull;          // acc==0 <-> h==0 baseline: exact
    __syncthreads();

    float acc = 0.f;
    float em = 1.0f;
    unsigned long long myold = 0ull;         // wave-uniform; used by lane0 only

    for (int t = 0; t < T; ++t) {
        const float u = kk * fmaf(a, v, m * em);
        const unsigned long long hb = __ballot(u > 0.f);
        const unsigned long long sb = __ballot(u > Vth);
        const int p = t & 1;
        if (lane == 0) {
            lmask[p][w] = hb;
            ((unsigned char*)&lflag[p])[w] = (hb != myold) ? (unsigned char)1 : (unsigned char)0;
            *(unsigned long long*)(sp + ((size_t)t * NN + r) * 16 + 2 * w) = sb;
            myold = hb;
        }
        __syncthreads();   // B1: masks/flags visible

        if (lflag[p] != 0ull) {
            // per-word change counts (every thread, static unroll)
            int cN[1];  (void)cN;
            const unsigned long long n0 = lmask[p][0], n1 = lmask[p][1],
                n2 = lmask[p][2], n3 = lmask[p][3], n4 = lmask[p][4],
                n5 = lmask[p][5], n6 = lmask[p][6], n7 = lmask[p][7];
            const int c0 = __popcll(n0 ^ omask[0]);
            const int c1 = __popcll(n1 ^ omask[1]);
            const int c2 = __popcll(n2 ^ omask[2]);
            const int c3 = __popcll(n3 ^ omask[3]);
            const int c4 = __popcll(n4 ^ omask[4]);
            const int c5 = __popcll(n5 ^ omask[5]);
            const int c6 = __popcll(n6 ^ omask[6]);
            const int c7 = __popcll(n7 ^ omask[7]);
            const int ntot = c0 + c1 + c2 + c3 + c4 + c5 + c6 + c7;
            int base = 0;
            if (w > 0) base += c0;
            if (w > 1) base += c1;
            if (w > 2) base += c2;
            if (w > 3) base += c3;
            if (w > 4) base += c4;
            if (w > 5) base += c5;
            if (w > 6) base += c6;

            // own wave's words via dynamic LDS index (allowed)
            const unsigned long long nw = lmask[p][w];
            const unsigned long long xw = nw ^ omask[w];
            if ((xw >> lane) & 1ull) {
                const int pos = (int)__popcll(xw & ((1ull << lane) - 1ull));
                const unsigned row = (unsigned)((w << 6) + lane);
                const unsigned sgn = (unsigned)((nw >> lane) & 1ull) << 15;
                list[base + pos] = (unsigned short)(row | sgn);
            }
            __syncthreads();   // B2: list ready

            if (lane == 0) omask[w] = nw;   // next read is after a later B1

            for (int j = 0; j < ntot; j += 32) {
                const uint4 le0 = *(const uint4*)(list + j);
                const uint4 le1 = *(const uint4*)(list + j + 8);
                const uint4 le2 = *(const uint4*)(list + j + 16);
                const uint4 le3 = *(const uint4*)(list + j + 24);
                unsigned ent[32];
                ent[0]  = le0.x & 0xFFFFu; ent[1]  = le0.x >> 16;
                ent[2]  = le0.y & 0xFFFFu; ent[3]  = le0.y >> 16;
                ent[4]  = le0.z & 0xFFFFu; ent[5]  = le0.z >> 16;
                ent[6]  = le0.w & 0xFFFFu; ent[7]  = le0.w >> 16;
                ent[8]  = le1.x & 0xFFFFu; ent[9]  = le1.x >> 16;
                ent[10] = le1.y & 0xFFFFu; ent[11] = le1.y >> 16;
                ent[12] = le1.z & 0xFFFFu; ent[13] = le1.z >> 16;
                ent[14] = le1.w & 0xFFFFu; ent[15] = le1.w >> 16;
                ent[16] = le2.x & 0xFFFFu; ent[17] = le2.x >> 16;
                ent[18] = le2.y & 0xFFFFu; ent[19] = le2.y >> 16;
                ent[20] = le2.z & 0xFFFFu; ent[21] = le2.z >> 16;
                ent[22] = le2.w & 0xFFFFu; ent[23] = le2.w >> 16;
                ent[24] = le3.x & 0xFFFFu; ent[25] = le3.x >> 16;
                ent[26] = le3.y & 0xFFFFu; ent[27] = le3.y >> 16;
                ent[28] = le3.z & 0xFFFFu; ent[29] = le3.z >> 16;
                ent[30] = le3.w & 0xFFFFu; ent[31] = le3.w >> 16;
                float g[32];
#pragma unroll
                for (int i = 0; i < 32; ++i)
                    g[i] = Gc[((size_t)(ent[i] & 511u)) << 9];
#pragma unroll
                for (int i = 0; i < 32; ++i) {
                    const float sgv = (ent[i] & 0x8000u) ? g[i] : -g[i];
                    acc += (j + i < ntot) ? sgv : 0.0f;
                }
            }
        }

        v = fmaf(dd, v, fmaf(e, acc, cg));
        em *= dd;
    }
}

// ---- Expand: out[t][b][o] = bit b of sp[t][o]. Coalesced float4 stores.
__global__ __launch_bounds__(256) void expand_kernel(
    const unsigned* __restrict__ sp, float* __restrict__ out)
{
    const int tid = threadIdx.x;
    const int t = blockIdx.x >> 3;
    const int bt8 = blockIdx.x & 7;

    __shared__ uint2 sh[NN];
    const uint2* spw = (const uint2*)sp;
    sh[tid]       = spw[((size_t)t * NN + tid) * 8 + bt8];
    sh[tid + 256] = spw[((size_t)t * NN + tid + 256) * 8 + bt8];
    __syncthreads();

    const int b = bt8 * 64 + (tid >> 2);
    const int sub = tid & 3;
    const int rw = (tid >> 2) >> 5;
    const int bit = b & 31;
    float* op = out + (size_t)t * (NN * NN) + (size_t)b * NN;

#pragma unroll 4
    for (int i = 0; i < 32; ++i) {
        const int o = sub * 4 + i * 16;
        const uint2 w0 = sh[o];
        const uint2 w1 = sh[o + 1];
        const uint2 w2 = sh[o + 2];
        const uint2 w3 = sh[o + 3];
        float4 f;
        f.x = (float)(((rw ? w0.y : w0.x) >> bit) & 1u);
        f.y = (float)(((rw ? w1.y : w1.x) >> bit) & 1u);
        f.z = (float)(((rw ? w2.y : w2.x) >> bit) & 1u);
        f.w = (float)(((rw ? w3.y : w3.x) >> bit) & 1u);
        *(float4*)(op + o) = f;
    }
}

// ================= Fallback path (tiny ws): fused full-K gemm + colsum +
// round-1 step kernel (direct strided writes). Needs 3 MB + 2 KB of ws.
__global__ __launch_bounds__(256) void gemm32_fused_kernel(
    const float* __restrict__ x, const float* __restrict__ W,
    const float* __restrict__ P0, const float* __restrict__ bias,
    float* __restrict__ M, float* __restrict__ V0, float* __restrict__ G)
{
    const int tid = threadIdx.x;
    const int bid = blockIdx.x;
    const bool isG = bid >= 256;
    const int tb = isG ? bid - 256 : bid;
    const bool dual = !isG;

    const float* A1 = isG ? x : W;
    const float* Bm = x;
    float* D1 = isG ? G : M;

    const int tx = tid & 15;
    const int ty = tid >> 4;
    const int rb = (tb >> 4) << 5;
    const int cb = (tb & 15) << 5;

    __shared__ float A1t[64][36];
    __shared__ float A2t[64][36];
    __shared__ float Bt[64][36];

    float acc1[2][2] = {{0.f, 0.f}, {0.f, 0.f}};
    float acc2[2][2] = {{0.f, 0.f}, {0.f, 0.f}};

    const int lrow = tid >> 3;
    const int lk = (tid & 7) << 2;

    for (int k0 = 0; k0 < NN; k0 += 64) {
        const float4 a1a = *(const float4*)(A1 + (size_t)(rb + lrow) * NN + k0 + lk);
        const float4 a1b = *(const float4*)(A1 + (size_t)(rb + lrow) * NN + k0 + lk + 32);
        const float4 bva = *(const float4*)(Bm + (size_t)(cb + lrow) * NN + k0 + lk);
        const float4 bvb = *(const float4*)(Bm + (size_t)(cb + lrow) * NN + k0 + lk + 32);
        float4 a2a = make_float4(0.f, 0.f, 0.f, 0.f), a2b = a2a;
        if (dual) {
            a2a = *(const float4*)(P0 + (size_t)(rb + lrow) * NN + k0 + lk);
            a2b = *(const float4*)(P0 + (size_t)(rb + lrow) * NN + k0 + lk + 32);
        }
        __syncthreads();
        A1t[lk + 0][lrow] = a1a.x; A1t[lk + 1][lrow] = a1a.y;
        A1t[lk + 2][lrow] = a1a.z; A1t[lk + 3][lrow] = a1a.w;
        A1t[lk + 32][lrow] = a1b.x; A1t[lk + 33][lrow] = a1b.y;
        A1t[lk + 34][lrow] = a1b.z; A1t[lk + 35][lrow] = a1b.w;
        Bt[lk + 0][lrow] = bva.x; Bt[lk + 1][lrow] = bva.y;
        Bt[lk + 2][lrow] = bva.z; Bt[lk + 3][lrow] = bva.w;
        Bt[lk + 32][lrow] = bvb.x; Bt[lk + 33][lrow] = bvb.y;
        Bt[lk + 34][lrow] = bvb.z; Bt[lk + 35][lrow] = bvb.w;
        if (dual) {
            A2t[lk + 0][lrow] = a2a.x; A2t[lk + 1][lrow] = a2a.y;
            A2t[lk + 2][lrow] = a2a.z; A2t[lk + 3][lrow] = a2a.w;
            A2t[lk + 32][lrow] = a2b.x; A2t[lk + 33][lrow] = a2b.y;
            A2t[lk + 34][lrow] = a2b.z; A2t[lk + 35][lrow] = a2b.w;
        }
        __syncthreads();

#pragma unroll
        for (int k = 0; k < 64; ++k) {
            const float2 av = *(const float2*)&A1t[k][2 * ty];
            const float2 bw = *(const float2*)&Bt[k][2 * tx];
            acc1[0][0] = fmaf(av.x, bw.x, acc1[0][0]);
            acc1[0][1] = fmaf(av.x, bw.y, acc1[0][1]);
            acc1[1][0] = fmaf(av.y, bw.x, acc1[1][0]);
            acc1[1][1] = fmaf(av.y, bw.y, acc1[1][1]);
            if (dual) {
                const float2 cv = *(const float2*)&A2t[k][2 * ty];
                acc2[0][0] = fmaf(cv.x, bw.x, acc2[0][0]);
                acc2[0][1] = fmaf(cv.x, bw.y, acc2[0][1]);
                acc2[1][0] = fmaf(cv.y, bw.x, acc2[1][0]);
                acc2[1][1] = fmaf(cv.y, bw.y, acc2[1][1]);
            }
        }
    }

#pragma unroll
    for (int i = 0; i < 2; ++i) {
        const int r = rb + 2 * ty + i;
        float2 o = make_float2(acc1[i][0], acc1[i][1]);
        if (dual) {
            const float bb = bias[r];
            o.x = fmaxf(o.x + bb, 0.f);
            o.y = fmaxf(o.y + bb, 0.f);
        }
        *(float2*)(D1 + (size_t)r * NN + cb + 2 * tx) = o;
        if (dual) {
            *(float2*)(V0 + (size_t)r * NN + cb + 2 * tx) = make_float2(acc2[i][0], acc2[i][1]);
        }
    }
}

__global__ __launch_bounds__(256) void snn_step_kernel(
    const float* __restrict__ M, const float* __restrict__ G,
    const float* __restrict__ V0, const float* __restrict__ gs,
    const float* __restrict__ alpha, const float* __restrict__ eta,
    const float* __restrict__ beta, float* __restrict__ out, int T)
{
    const int j = threadIdx.x;
    const int r0 = blockIdx.x * 2;
    const int c0 = 2 * j;
    const float a = alpha[0], e = eta[0], bt = beta[0];
    const float kk = 0.2f, dd = 0.36787944117144233f, Vth = 0.2f;

    float v00 = V0[r0 * NN + c0];
    float v01 = V0[r0 * NN + c0 + 1];
    float v10 = V0[(r0 + 1) * NN + c0];
    float v11 = V0[(r0 + 1) * NN + c0 + 1];
    const float m00 = M[r0 * NN + c0];
    const float m01 = M[r0 * NN + c0 + 1];
    const float m10 = M[(r0 + 1) * NN + c0];
    const float m11 = M[(r0 + 1) * NN + c0 + 1];
    const float gs0 = gs[c0];
    const float gs1 = gs[c0 + 1];

    __shared__ float2 hp[NN];
    float em = 1.0f;
    const float2* Gcol = (const float2*)G + j;

    for (int t = 0; t < T; ++t) {
        const float u00 = kk * (m00 * em + a * v00);
        const float u01 = kk * (m01 * em + a * v01);
        const float u10 = kk * (m10 * em + a * v10);
        const float u11 = kk * (m11 * em + a * v11);

        float* outp = out + (size_t)t * (NN * NN);
        float2 sA = make_float2(u00 > Vth ? 1.f : 0.f, u10 > Vth ? 1.f : 0.f);
        float2 sB = make_float2(u01 > Vth ? 1.f : 0.f, u11 > Vth ? 1.f : 0.f);
        *(float2*)(outp + (size_t)c0 * NN + r0) = sA;
        *(float2*)(outp + (size_t)(c0 + 1) * NN + r0) = sB;

        hp[c0]     = make_float2(u00 > 0.f ? 1.f : 0.f, u10 > 0.f ? 1.f : 0.f);
        hp[c0 + 1] = make_float2(u01 > 0.f ? 1.f : 0.f, u11 > 0.f ? 1.f : 0.f);
        __syncthreads();

        float acc00 = 0.f, acc01 = 0.f, acc10 = 0.f, acc11 = 0.f;
#pragma unroll 8
        for (int bp = 0; bp < NN; ++bp) {
            float2 h = hp[bp];
            float2 g = Gcol[(size_t)bp * 256];
            acc00 = fmaf(h.x, g.x, acc00);
            acc01 = fmaf(h.x, g.y, acc01);
            acc10 = fmaf(h.y, g.x, acc10);
            acc11 = fmaf(h.y, g.y, acc11);
        }

        v00 = dd * v00 + e * (acc00 + bt * gs0);
        v01 = dd * v01 + e * (acc01 + bt * gs1);
        v10 = dd * v10 + e * (acc10 + bt * gs0);
        v11 = dd * v11 + e * (acc11 + bt * gs1);
        em *= dd;
        __syncthreads();
    }
}

extern "C" void kernel_launch(void* const* d_in, const int* in_sizes, int n_in,
                              void* d_out, int out_size, void* d_ws, size_t ws_size,
                              hipStream_t stream)
{
    const float* x     = (const float*)d_in[0];
    const float* W     = (const float*)d_in[1];
    const float* bias  = (const float*)d_in[2];
    const float* alpha = (const float*)d_in[3];
    const float* eta   = (const float*)d_in[4];
    const float* beta  = (const float*)d_in[5];
    const float* P0    = (const float*)d_in[6];
    (void)in_sizes; (void)n_in;

    const int T = out_size / (NN * NN);

    float* ws   = (float*)d_ws;
    float* M1   = ws;                           // 6 split partials, 1 MB each
    float* M2   = ws + 1 * NN * NN;
    float* V01  = ws + 2 * NN * NN;
    float* V02  = ws + 3 * NN * NN;
    float* G1   = ws + 4 * NN * NN;
    float* G2   = ws + 5 * NN * NN;
    float* G    = ws + 6 * NN * NN;             // combined G, 1 MB
    float* gsv  = ws + 7 * NN * NN;             // [512]
    unsigned* sp = (unsigned*)(gsv + NN);       // [T][512][16] words

    const size_t need_main = ((size_t)7 * NN * NN + NN) * 4 + (size_t)T * NN * 16 * 4;

    if (ws_size >= need_main) {
        hipLaunchKernelGGL(gemm_dual_split_kernel, dim3(512), dim3(256), 0, stream,
                           x, W, P0, M1, M2, V01, V02, G1, G2);
        hipLaunchKernelGGL(combine_kernel, dim3(256), dim3(256), 0, stream,
                           (const float4*)G1, (const float4*)G2, (float4*)G);
        hipLaunchKernelGGL(colsum_kernel, dim3(8), dim3(256), 0, stream, G, gsv);
        hipLaunchKernelGGL(snn_bits5_kernel, dim3(NN), dim3(512), 0, stream,
                           M1, M2, bias, G, V01, V02, gsv, alpha, eta, beta, sp, T);
        hipLaunchKernelGGL(expand_kernel, dim3(T * 8), dim3(256), 0, stream,
                           sp, (float*)d_out);
    } else {
        float* M  = ws;
        float* V0 = ws + NN * NN;
        float* Gf = ws + 2 * NN * NN;
        float* gs2 = ws + 3 * NN * NN;
        hipLaunchKernelGGL(gemm32_fused_kernel, dim3(512), dim3(256), 0, stream,
                           x, W, P0, bias, M, V0, Gf);
        hipLaunchKernelGGL(colsum_kernel, dim3(8), dim3(256), 0, stream, Gf, gs2);
        hipLaunchKernelGGL(snn_step_kernel, dim3(256), dim3(256), 0, stream,
                           M, Gf, V0, gs2, alpha, eta, beta, (float*)d_out, T);
    }
}

// Round 12
// 141.709 us; speedup vs baseline: 1.1426x; 1.1426x over previous
//
#include <hip/hip_runtime.h>

// B = IN = OUT = 512; T from out_size.
// v_t = P_t @ x^T [OUT,B]; G = x@x^T [B,B]
//   u = k*(M*e^{-t} + a*v);  h = (u>0);  s = (u>0.2)
//   v' = d*v + e*(h@G + bt*colsum(G))
// Round-12:
//  snn_bits6: same delta semantics as rounds 10/11 (ascending (word,lane),
//    sign = new h bit) but __launch_bounds__(512,4) so the 16-wide batched
//    apply actually lives in registers (round-11's VGPR=32 cap spilled the
//    batch arrays to scratch). Old masks in registers (wave-uniform), wcnt
//    published pre-barrier: 2 barriers transient, 1 frozen, minimal LDS.
//  gemm64: 64x64 tile, 4x4 micro, grid 192 (all co-resident), reg-dbuf
//    staging; k-order and bias/relu fusion identical to rounds 8-10 ->
//    M/V0/G bit-identical. No split partials, no combine kernel.

#define NN 512

// ---- gemm64: grid 192 = 3 outputs x (8x8 tiles of 64x64). 256 thr.
// out 0: M = relu(W·x^T + b); out 1: V0 = P0·x^T; out 2: G = x·x^T.
__global__ __launch_bounds__(256) void gemm64_kernel(
    const float* __restrict__ x, const float* __restrict__ W,
    const float* __restrict__ P0, const float* __restrict__ bias,
    float* __restrict__ M, float* __restrict__ V0, float* __restrict__ G)
{
    const int tid = threadIdx.x;
    const int bid = blockIdx.x;          // 0..191
    const int out = bid >> 6;            // 0..2
    const int tl = bid & 63;
    const int rb = (tl >> 3) << 6;       // 8 row-tiles of 64
    const int cb = (tl & 7) << 6;        // 8 col-tiles of 64

    const float* A = ((out == 0) ? W : (out == 1) ? P0 : x) + (size_t)rb * NN;
    const float* Bx = x + (size_t)cb * NN;
    float* D = (out == 0) ? M : (out == 1) ? V0 : G;

    const int tx = tid & 15;             // cols 4tx..4tx+3
    const int ty = tid >> 4;             // rows 4ty..4ty+3

    __shared__ float At[32][68];         // [k][row]; row-group offset 16B-aligned
    __shared__ float Bt[32][68];         // [k][col]

    const int lr = tid >> 2;             // 0..63
    const int lk = (tid & 3) << 3;       // 0,8,16,24

    float acc[4][4] = {{0.f,0.f,0.f,0.f},{0.f,0.f,0.f,0.f},
                       {0.f,0.f,0.f,0.f},{0.f,0.f,0.f,0.f}};

    // prologue: chunk 0 into registers
    float4 a0 = *(const float4*)(A + (size_t)lr * NN + lk);
    float4 a1 = *(const float4*)(A + (size_t)lr * NN + lk + 4);
    float4 b0 = *(const float4*)(Bx + (size_t)lr * NN + lk);
    float4 b1 = *(const float4*)(Bx + (size_t)lr * NN + lk + 4);

    for (int c = 0; c < 16; ++c) {
        __syncthreads();
        At[lk + 0][lr] = a0.x; At[lk + 1][lr] = a0.y;
        At[lk + 2][lr] = a0.z; At[lk + 3][lr] = a0.w;
        At[lk + 4][lr] = a1.x; At[lk + 5][lr] = a1.y;
        At[lk + 6][lr] = a1.z; At[lk + 7][lr] = a1.w;
        Bt[lk + 0][lr] = b0.x; Bt[lk + 1][lr] = b0.y;
        Bt[lk + 2][lr] = b0.z; Bt[lk + 3][lr] = b0.w;
        Bt[lk + 4][lr] = b1.x; Bt[lk + 5][lr] = b1.y;
        Bt[lk + 6][lr] = b1.z; Bt[lk + 7][lr] = b1.w;
        __syncthreads();

        if (c < 15) {   // next-chunk loads hide under the k-loop
            const int k0 = (c + 1) << 5;
            a0 = *(const float4*)(A + (size_t)lr * NN + k0 + lk);
            a1 = *(const float4*)(A + (size_t)lr * NN + k0 + lk + 4);
            b0 = *(const float4*)(Bx + (size_t)lr * NN + k0 + lk);
            b1 = *(const float4*)(Bx + (size_t)lr * NN + k0 + lk + 4);
        }

#pragma unroll
        for (int k = 0; k < 32; ++k) {
            const float4 av = *(const float4*)&At[k][4 * ty];
            const float4 bv = *(const float4*)&Bt[k][4 * tx];
            const float avs[4] = {av.x, av.y, av.z, av.w};
            const float bvs[4] = {bv.x, bv.y, bv.z, bv.w};
#pragma unroll
            for (int i = 0; i < 4; ++i)
#pragma unroll
                for (int j = 0; j < 4; ++j)
                    acc[i][j] = fmaf(avs[i], bvs[j], acc[i][j]);
        }
    }

#pragma unroll
    for (int i = 0; i < 4; ++i) {
        const int r = rb + 4 * ty + i;
        float4 o = make_float4(acc[i][0], acc[i][1], acc[i][2], acc[i][3]);
        if (out == 0) {
            const float bb = bias[r];
            o.x = fmaxf(o.x + bb, 0.f); o.y = fmaxf(o.y + bb, 0.f);
            o.z = fmaxf(o.z + bb, 0.f); o.w = fmaxf(o.w + bb, 0.f);
        }
        *(float4*)(D + (size_t)r * NN + cb + 4 * tx) = o;
    }
}

// ---- colsum: 8 blocks x 256 thr
__global__ __launch_bounds__(256) void colsum_kernel(
    const float* __restrict__ G, float* __restrict__ gs)
{
    __shared__ float red[4][64];
    const int tid = threadIdx.x;
    const int c = (blockIdx.x << 6) + (tid & 63);
    const int g = tid >> 6;
    float s = 0.f;
    for (int bp = 128 * g; bp < 128 * g + 128; ++bp) s += G[(size_t)bp * NN + c];
    if (g > 0) red[g][tid & 63] = s;
    __syncthreads();
    if (g == 0) gs[c] = ((s + red[1][tid & 63]) + red[2][tid & 63]) + red[3][tid & 63];
}

// ---- Main recurrence: 512 blocks x 512 threads. Thread owns col c = tid.
// Old h-words live in registers (wave-uniform). lane0 publishes per-wave flip
// count + flag BEFORE the barrier. Frozen: 1 barrier. Transient: list build
// (barrier 2) then 16-wide register-resident batched apply.
__global__ __launch_bounds__(512, 4) void snn_bits6_kernel(
    const float* __restrict__ M, const float* __restrict__ G,
    const float* __restrict__ V0, const float* __restrict__ gs,
    const float* __restrict__ alpha, const float* __restrict__ eta,
    const float* __restrict__ beta, unsigned* __restrict__ sp, int T)
{
    const int tid = threadIdx.x;
    const int w = tid >> 6;
    const int lane = tid & 63;
    const int r = blockIdx.x;

    __shared__ unsigned long long lflag[2];
    __shared__ int wcnt[8];
    __shared__ unsigned short list[528] __attribute__((aligned(16)));

    const float a = alpha[0], e = eta[0], bt = beta[0];
    const float kk = 0.2f;
    const float dd = 0.36787944117144233f;   // exp(-1)
    const float Vth = 0.2f;

    const size_t rc = (size_t)r * NN + tid;
    const float m = M[rc];
    float v = V0[rc];
    const float cg = e * bt * gs[tid];
    const float* Gc = G + tid;

    float acc = 0.f;
    float em = 1.0f;
    unsigned long long oldw = 0ull;      // own wave's last-applied word (uniform)

    for (int t = 0; t < T; ++t) {
        const float u = kk * fmaf(a, v, m * em);
        const unsigned long long hb = __ballot(u > 0.f);
        const unsigned long long sb = __ballot(u > Vth);
        const unsigned long long xw = hb ^ oldw;
        const int p = t & 1;
        if (lane == 0) {
            ((unsigned char*)&lflag[p])[w] = (xw != 0ull) ? (unsigned char)1 : (unsigned char)0;
            wcnt[w] = (int)__popcll(xw);
            *(unsigned long long*)(sp + ((size_t)t * NN + r) * 16 + 2 * w) = sb;
        }
        __syncthreads();   // B1

        if (lflag[p] != 0ull) {
            const int c0 = wcnt[0], c1 = wcnt[1], c2 = wcnt[2], c3 = wcnt[3];
            const int c4 = wcnt[4], c5 = wcnt[5], c6 = wcnt[6], c7 = wcnt[7];
            const int ntot = ((c0 + c1) + (c2 + c3)) + ((c4 + c5) + (c6 + c7));
            int base = 0;
            if (w > 0) base += c0;
            if (w > 1) base += c1;
            if (w > 2) base += c2;
            if (w > 3) base += c3;
            if (w > 4) base += c4;
            if (w > 5) base += c5;
            if (w > 6) base += c6;

            if ((xw >> lane) & 1ull) {
                const int pos = (int)__popcll(xw & ((1ull << lane) - 1ull));
                const unsigned row = (unsigned)((w << 6) + lane);
                const unsigned sgn = (unsigned)((hb >> lane) & 1ull) << 15;
                list[base + pos] = (unsigned short)(row | sgn);
            }
            __syncthreads();   // B2: list ready

            for (int j = 0; j < ntot; j += 16) {
                const uint4 leA = *(const uint4*)(list + j);
                const uint4 leB = *(const uint4*)(list + j + 8);
                unsigned ent[16];
                ent[0]  = leA.x & 0xFFFFu; ent[1]  = leA.x >> 16;
                ent[2]  = leA.y & 0xFFFFu; ent[3]  = leA.y >> 16;
                ent[4]  = leA.z & 0xFFFFu; ent[5]  = leA.z >> 16;
                ent[6]  = leA.w & 0xFFFFu; ent[7]  = leA.w >> 16;
                ent[8]  = leB.x & 0xFFFFu; ent[9]  = leB.x >> 16;
                ent[10] = leB.y & 0xFFFFu; ent[11] = leB.y >> 16;
                ent[12] = leB.z & 0xFFFFu; ent[13] = leB.z >> 16;
                ent[14] = leB.w & 0xFFFFu; ent[15] = leB.w >> 16;
                float g[16];
#pragma unroll
                for (int i = 0; i < 16; ++i)
                    g[i] = Gc[((size_t)(ent[i] & 511u)) << 9];
#pragma unroll
                for (int i = 0; i < 16; ++i) {
                    const float sgv = (ent[i] & 0x8000u) ? g[i] : -g[i];
                    acc += (j + i < ntot) ? sgv : 0.0f;
                }
            }
        }

        oldw = hb;
        v = fmaf(dd, v, fmaf(e, acc, cg));
        em *= dd;
    }
}

// ---- Expand: out[t][b][o] = bit b of sp[t][o]. Coalesced float4 stores.
__global__ __launch_bounds__(256) void expand_kernel(
    const unsigned* __restrict__ sp, float* __restrict__ out)
{
    const int tid = threadIdx.x;
    const int t = blockIdx.x >> 3;
    const int bt8 = blockIdx.x & 7;

    __shared__ uint2 sh[NN];
    const uint2* spw = (const uint2*)sp;
    sh[tid]       = spw[((size_t)t * NN + tid) * 8 + bt8];
    sh[tid + 256] = spw[((size_t)t * NN + tid + 256) * 8 + bt8];
    __syncthreads();

    const int b = bt8 * 64 + (tid >> 2);
    const int sub = tid & 3;
    const int rw = (tid >> 2) >> 5;
    const int bit = b & 31;
    float* op = out + (size_t)t * (NN * NN) + (size_t)b * NN;

#pragma unroll 4
    for (int i = 0; i < 32; ++i) {
        const int o = sub * 4 + i * 16;
        const uint2 w0 = sh[o];
        const uint2 w1 = sh[o + 1];
        const uint2 w2 = sh[o + 2];
        const uint2 w3 = sh[o + 3];
        float4 f;
        f.x = (float)(((rw ? w0.y : w0.x) >> bit) & 1u);
        f.y = (float)(((rw ? w1.y : w1.x) >> bit) & 1u);
        f.z = (float)(((rw ? w2.y : w2.x) >> bit) & 1u);
        f.w = (float)(((rw ? w3.y : w3.x) >> bit) & 1u);
        *(float4*)(op + o) = f;
    }
}

// ---- Fallback (tiny ws): round-1 step kernel with direct strided writes.
__global__ __launch_bounds__(256) void snn_step_kernel(
    const float* __restrict__ M, const float* __restrict__ G,
    const float* __restrict__ V0, const float* __restrict__ gs,
    const float* __restrict__ alpha, const float* __restrict__ eta,
    const float* __restrict__ beta, float* __restrict__ out, int T)
{
    const int j = threadIdx.x;
    const int r0 = blockIdx.x * 2;
    const int c0 = 2 * j;
    const float a = alpha[0], e = eta[0], bt = beta[0];
    const float kk = 0.2f, dd = 0.36787944117144233f, Vth = 0.2f;

    float v00 = V0[r0 * NN + c0];
    float v01 = V0[r0 * NN + c0 + 1];
    float v10 = V0[(r0 + 1) * NN + c0];
    float v11 = V0[(r0 + 1) * NN + c0 + 1];
    const float m00 = M[r0 * NN + c0];
    const float m01 = M[r0 * NN + c0 + 1];
    const float m10 = M[(r0 + 1) * NN + c0];
    const float m11 = M[(r0 + 1) * NN + c0 + 1];
    const float gs0 = gs[c0];
    const float gs1 = gs[c0 + 1];

    __shared__ float2 hp[NN];
    float em = 1.0f;
    const float2* Gcol = (const float2*)G + j;

    for (int t = 0; t < T; ++t) {
        const float u00 = kk * (m00 * em + a * v00);
        const float u01 = kk * (m01 * em + a * v01);
        const float u10 = kk * (m10 * em + a * v10);
        const float u11 = kk * (m11 * em + a * v11);

        float* outp = out + (size_t)t * (NN * NN);
        float2 sA = make_float2(u00 > Vth ? 1.f : 0.f, u10 > Vth ? 1.f : 0.f);
        float2 sB = make_float2(u01 > Vth ? 1.f : 0.f, u11 > Vth ? 1.f : 0.f);
        *(float2*)(outp + (size_t)c0 * NN + r0) = sA;
        *(float2*)(outp + (size_t)(c0 + 1) * NN + r0) = sB;

        hp[c0]     = make_float2(u00 > 0.f ? 1.f : 0.f, u10 > 0.f ? 1.f : 0.f);
        hp[c0 + 1] = make_float2(u01 > 0.f ? 1.f : 0.f, u11 > 0.f ? 1.f : 0.f);
        __syncthreads();

        float acc00 = 0.f, acc01 = 0.f, acc10 = 0.f, acc11 = 0.f;
#pragma unroll 8
        for (int bp = 0; bp < NN; ++bp) {
            float2 h = hp[bp];
            float2 g = Gcol[(size_t)bp * 256];
            acc00 = fmaf(h.x, g.x, acc00);
            acc01 = fmaf(h.x, g.y, acc01);
            acc10 = fmaf(h.y, g.x, acc10);
            acc11 = fmaf(h.y, g.y, acc11);
        }

        v00 = dd * v00 + e * (acc00 + bt * gs0);
        v01 = dd * v01 + e * (acc01 + bt * gs1);
        v10 = dd * v10 + e * (acc10 + bt * gs0);
        v11 = dd * v11 + e * (acc11 + bt * gs1);
        em *= dd;
        __syncthreads();
    }
}

extern "C" void kernel_launch(void* const* d_in, const int* in_sizes, int n_in,
                              void* d_out, int out_size, void* d_ws, size_t ws_size,
                              hipStream_t stream)
{
    const float* x     = (const float*)d_in[0];
    const float* W     = (const float*)d_in[1];
    const float* bias  = (const float*)d_in[2];
    const float* alpha = (const float*)d_in[3];
    const float* eta   = (const float*)d_in[4];
    const float* beta  = (const float*)d_in[5];
    const float* P0    = (const float*)d_in[6];
    (void)in_sizes; (void)n_in;

    const int T = out_size / (NN * NN);

    float* ws  = (float*)d_ws;
    float* M   = ws;                           // [512,512] final (relu+bias)
    float* V0  = ws + NN * NN;                 // [512,512]
    float* G   = ws + 2 * NN * NN;             // [512,512] = 1 MB
    float* gsv = ws + 3 * NN * NN;             // [512]
    unsigned* sp = (unsigned*)(gsv + NN);      // [T][512][16] words

    const size_t need_main = ((size_t)3 * NN * NN + NN) * 4 + (size_t)T * NN * 16 * 4;

    hipLaunchKernelGGL(gemm64_kernel, dim3(192), dim3(256), 0, stream,
                       x, W, P0, bias, M, V0, G);
    hipLaunchKernelGGL(colsum_kernel, dim3(8), dim3(256), 0, stream, G, gsv);

    if (ws_size >= need_main) {
        hipLaunchKernelGGL(snn_bits6_kernel, dim3(NN), dim3(512), 0, stream,
                           M, G, V0, gsv, alpha, eta, beta, sp, T);
        hipLaunchKernelGGL(expand_kernel, dim3(T * 8), dim3(256), 0, stream,
                           sp, (float*)d_out);
    } else {
        hipLaunchKernelGGL(snn_step_kernel, dim3(256), dim3(256), 0, stream,
                           M, G, V0, gsv, alpha, eta, beta, (float*)d_out, T);
    }
}

// Round 13
// 131.157 us; speedup vs baseline: 1.2345x; 1.0804x over previous
//
#include <hip/hip_runtime.h>

// B = IN = OUT = 512; T from out_size.
// v_t = P_t @ x^T [OUT,B]; G = x@x^T [B,B]
//   u = k*(M*e^{-t} + a*v);  h = (u>0);  s = (u>0.2)
//   v' = d*v + e*(h@G + bt*colsum(G))
// Round-13:
//  acc0_kernel: t=0's bulk apply (h0@G, ~256 rows/block = 256 MB of
//    latency-serialized L2 reads inside snn) is hoisted into a dense tiled
//    GEMM with proper LDS reuse (h0 = (k*(M + a*V0) > 0) is t-independent).
//  snn_bits7: t=0 loads acc from ACC0; t>=1 deltas applied with NAMED
//    scalars + 8 independent partial accumulators (rounds 10-12's array
//    batches were re-rolled by the compiler into serial load-add chains --
//    VGPR=20 proved the batch never lived in registers).

#define NN 512

// ---- gemm64: grid 192 = 3 outputs x (8x8 tiles of 64x64). 256 thr.
// out 0: M = relu(W·x^T + b); out 1: V0 = P0·x^T; out 2: G = x·x^T.
__global__ __launch_bounds__(256) void gemm64_kernel(
    const float* __restrict__ x, const float* __restrict__ W,
    const float* __restrict__ P0, const float* __restrict__ bias,
    float* __restrict__ M, float* __restrict__ V0, float* __restrict__ G)
{
    const int tid = threadIdx.x;
    const int bid = blockIdx.x;          // 0..191
    const int out = bid >> 6;            // 0..2
    const int tl = bid & 63;
    const int rb = (tl >> 3) << 6;       // 8 row-tiles of 64
    const int cb = (tl & 7) << 6;        // 8 col-tiles of 64

    const float* A = ((out == 0) ? W : (out == 1) ? P0 : x) + (size_t)rb * NN;
    const float* Bx = x + (size_t)cb * NN;
    float* D = (out == 0) ? M : (out == 1) ? V0 : G;

    const int tx = tid & 15;             // cols 4tx..4tx+3
    const int ty = tid >> 4;             // rows 4ty..4ty+3

    __shared__ float At[32][68];
    __shared__ float Bt[32][68];

    const int lr = tid >> 2;             // 0..63
    const int lk = (tid & 3) << 3;       // 0,8,16,24

    float acc[4][4] = {{0.f,0.f,0.f,0.f},{0.f,0.f,0.f,0.f},
                       {0.f,0.f,0.f,0.f},{0.f,0.f,0.f,0.f}};

    float4 a0 = *(const float4*)(A + (size_t)lr * NN + lk);
    float4 a1 = *(const float4*)(A + (size_t)lr * NN + lk + 4);
    float4 b0 = *(const float4*)(Bx + (size_t)lr * NN + lk);
    float4 b1 = *(const float4*)(Bx + (size_t)lr * NN + lk + 4);

    for (int c = 0; c < 16; ++c) {
        __syncthreads();
        At[lk + 0][lr] = a0.x; At[lk + 1][lr] = a0.y;
        At[lk + 2][lr] = a0.z; At[lk + 3][lr] = a0.w;
        At[lk + 4][lr] = a1.x; At[lk + 5][lr] = a1.y;
        At[lk + 6][lr] = a1.z; At[lk + 7][lr] = a1.w;
        Bt[lk + 0][lr] = b0.x; Bt[lk + 1][lr] = b0.y;
        Bt[lk + 2][lr] = b0.z; Bt[lk + 3][lr] = b0.w;
        Bt[lk + 4][lr] = b1.x; Bt[lk + 5][lr] = b1.y;
        Bt[lk + 6][lr] = b1.z; Bt[lk + 7][lr] = b1.w;
        __syncthreads();

        if (c < 15) {
            const int k0 = (c + 1) << 5;
            a0 = *(const float4*)(A + (size_t)lr * NN + k0 + lk);
            a1 = *(const float4*)(A + (size_t)lr * NN + k0 + lk + 4);
            b0 = *(const float4*)(Bx + (size_t)lr * NN + k0 + lk);
            b1 = *(const float4*)(Bx + (size_t)lr * NN + k0 + lk + 4);
        }

#pragma unroll
        for (int k = 0; k < 32; ++k) {
            const float4 av = *(const float4*)&At[k][4 * ty];
            const float4 bv = *(const float4*)&Bt[k][4 * tx];
            const float avs[4] = {av.x, av.y, av.z, av.w};
            const float bvs[4] = {bv.x, bv.y, bv.z, bv.w};
#pragma unroll
            for (int i = 0; i < 4; ++i)
#pragma unroll
                for (int j = 0; j < 4; ++j)
                    acc[i][j] = fmaf(avs[i], bvs[j], acc[i][j]);
        }
    }

#pragma unroll
    for (int i = 0; i < 4; ++i) {
        const int r = rb + 4 * ty + i;
        float4 o = make_float4(acc[i][0], acc[i][1], acc[i][2], acc[i][3]);
        if (out == 0) {
            const float bb = bias[r];
            o.x = fmaxf(o.x + bb, 0.f); o.y = fmaxf(o.y + bb, 0.f);
            o.z = fmaxf(o.z + bb, 0.f); o.w = fmaxf(o.w + bb, 0.f);
        }
        *(float4*)(D + (size_t)r * NN + cb + 4 * tx) = o;
    }
}

// ---- acc0: ACC0[r,c] = sum_b H0[r,b]*G[b,c], H0 = (kk*fmaf(a,V0,M) > 0).
// 32x32 tiles, grid 256, 256 thr, 2x2 micro, KC=32 (NN-form GEMM).
__global__ __launch_bounds__(256) void acc0_kernel(
    const float* __restrict__ M, const float* __restrict__ V0,
    const float* __restrict__ G, const float* __restrict__ alpha,
    float* __restrict__ ACC0)
{
    const int tid = threadIdx.x;
    const int rb = (blockIdx.x >> 4) << 5;
    const int cb = (blockIdx.x & 15) << 5;
    const float a = alpha[0];
    const float kk = 0.2f;

    __shared__ float Ht[32][36];    // [k][r]
    __shared__ float Bt[32][36];    // [k][c]

    const int tx = tid & 15;        // cols 2tx,2tx+1
    const int ty = tid >> 4;        // rows 2ty,2ty+1
    const int lr = tid >> 3;        // 0..31
    const int lk = (tid & 7) << 2;  // 0,4,...,28

    float acc[2][2] = {{0.f, 0.f}, {0.f, 0.f}};

    for (int k0 = 0; k0 < NN; k0 += 32) {
        const float4 mv = *(const float4*)(M + (size_t)(rb + lr) * NN + k0 + lk);
        const float4 vv = *(const float4*)(V0 + (size_t)(rb + lr) * NN + k0 + lk);
        const float4 gv = *(const float4*)(G + (size_t)(k0 + lr) * NN + cb + lk);
        __syncthreads();
        Ht[lk + 0][lr] = (kk * fmaf(a, vv.x, mv.x) > 0.f) ? 1.f : 0.f;
        Ht[lk + 1][lr] = (kk * fmaf(a, vv.y, mv.y) > 0.f) ? 1.f : 0.f;
        Ht[lk + 2][lr] = (kk * fmaf(a, vv.z, mv.z) > 0.f) ? 1.f : 0.f;
        Ht[lk + 3][lr] = (kk * fmaf(a, vv.w, mv.w) > 0.f) ? 1.f : 0.f;
        Bt[lr][lk + 0] = gv.x; Bt[lr][lk + 1] = gv.y;
        Bt[lr][lk + 2] = gv.z; Bt[lr][lk + 3] = gv.w;
        __syncthreads();

#pragma unroll
        for (int k = 0; k < 32; ++k) {
            const float2 av = *(const float2*)&Ht[k][2 * ty];
            const float2 bv = *(const float2*)&Bt[k][2 * tx];
            acc[0][0] = fmaf(av.x, bv.x, acc[0][0]);
            acc[0][1] = fmaf(av.x, bv.y, acc[0][1]);
            acc[1][0] = fmaf(av.y, bv.x, acc[1][0]);
            acc[1][1] = fmaf(av.y, bv.y, acc[1][1]);
        }
    }

#pragma unroll
    for (int i = 0; i < 2; ++i) {
        *(float2*)(ACC0 + (size_t)(rb + 2 * ty + i) * NN + cb + 2 * tx) =
            make_float2(acc[i][0], acc[i][1]);
    }
}

// ---- colsum: 8 blocks x 256 thr, independent pipelined loads.
__global__ __launch_bounds__(256) void colsum_kernel(
    const float* __restrict__ G, float* __restrict__ gs)
{
    __shared__ float red[4][64];
    const int tid = threadIdx.x;
    const int c = (blockIdx.x << 6) + (tid & 63);
    const int g = tid >> 6;
    float s = 0.f;
#pragma unroll 8
    for (int bp = 128 * g; bp < 128 * g + 128; ++bp) s += G[(size_t)bp * NN + c];
    if (g > 0) red[g][tid & 63] = s;
    __syncthreads();
    if (g == 0) gs[c] = ((s + red[1][tid & 63]) + red[2][tid & 63]) + red[3][tid & 63];
}

// ---- Main recurrence: 512 blocks x 512 threads. Thread owns col c = tid.
// t=0: spikes + acc := ACC0 (bulk apply precomputed by acc0_kernel).
// t>=1: frozen = 1 barrier; transient = list build + named-scalar 8-wide
// apply with 8 independent partial accumulators (no serial acc chain).
__global__ __launch_bounds__(512, 4) void snn_bits7_kernel(
    const float* __restrict__ M, const float* __restrict__ G,
    const float* __restrict__ V0, const float* __restrict__ ACC0,
    const float* __restrict__ gs, const float* __restrict__ alpha,
    const float* __restrict__ eta, const float* __restrict__ beta,
    unsigned* __restrict__ sp, int T)
{
    const int tid = threadIdx.x;
    const int w = tid >> 6;
    const int lane = tid & 63;
    const int r = blockIdx.x;

    __shared__ unsigned long long lflag[2];
    __shared__ int wcnt[8];
    __shared__ unsigned short list[528] __attribute__((aligned(16)));

    const float a = alpha[0], e = eta[0], bt = beta[0];
    const float kk = 0.2f;
    const float dd = 0.36787944117144233f;   // exp(-1)
    const float Vth = 0.2f;

    const size_t rc = (size_t)r * NN + tid;
    const float m = M[rc];
    float v = V0[rc];
    const float cg = e * bt * gs[tid];
    const float* Gc = G + tid;

    float acc;
    float em;
    unsigned long long oldw;

    // ---- t = 0: bulk apply comes from ACC0
    {
        const float u = kk * fmaf(a, v, m * 1.0f);
        const unsigned long long hb = __ballot(u > 0.f);
        const unsigned long long sb = __ballot(u > Vth);
        if (lane == 0)
            *(unsigned long long*)(sp + (size_t)r * 16 + 2 * w) = sb;
        oldw = hb;
        acc = ACC0[rc];
        v = fmaf(dd, v, fmaf(e, acc, cg));
        em = dd;
    }

    for (int t = 1; t < T; ++t) {
        const float u = kk * fmaf(a, v, m * em);
        const unsigned long long hb = __ballot(u > 0.f);
        const unsigned long long sb = __ballot(u > Vth);
        const unsigned long long xw = hb ^ oldw;
        const int p = t & 1;
        if (lane == 0) {
            ((unsigned char*)&lflag[p])[w] = (xw != 0ull) ? (unsigned char)1 : (unsigned char)0;
            wcnt[w] = (int)__popcll(xw);
            *(unsigned long long*)(sp + ((size_t)t * NN + r) * 16 + 2 * w) = sb;
        }
        __syncthreads();   // B1

        if (lflag[p] != 0ull) {
            const int c0 = wcnt[0], c1 = wcnt[1], c2 = wcnt[2], c3 = wcnt[3];
            const int c4 = wcnt[4], c5 = wcnt[5], c6 = wcnt[6], c7 = wcnt[7];
            const int ntot = ((c0 + c1) + (c2 + c3)) + ((c4 + c5) + (c6 + c7));
            int base = 0;
            if (w > 0) base += c0;
            if (w > 1) base += c1;
            if (w > 2) base += c2;
            if (w > 3) base += c3;
            if (w > 4) base += c4;
            if (w > 5) base += c5;
            if (w > 6) base += c6;

            if ((xw >> lane) & 1ull) {
                const int pos = (int)__popcll(xw & ((1ull << lane) - 1ull));
                const unsigned row = (unsigned)((w << 6) + lane);
                const unsigned sgn = (unsigned)((hb >> lane) & 1ull) << 15;
                list[base + pos] = (unsigned short)(row | sgn);
            }
            __syncthreads();   // B2: list ready

            float s0 = 0.f, s1 = 0.f, s2 = 0.f, s3 = 0.f;
            float s4 = 0.f, s5 = 0.f, s6 = 0.f, s7 = 0.f;
            for (int j = 0; j < ntot; j += 8) {
                const uint4 le = *(const uint4*)(list + j);
                const unsigned e0 = le.x & 0xFFFFu, e1 = le.x >> 16;
                const unsigned e2 = le.y & 0xFFFFu, e3 = le.y >> 16;
                const unsigned e4 = le.z & 0xFFFFu, e5 = le.z >> 16;
                const unsigned e6 = le.w & 0xFFFFu, e7 = le.w >> 16;
                const float g0 = Gc[(size_t)(e0 & 511u) << 9];
                const float g1 = Gc[(size_t)(e1 & 511u) << 9];
                const float g2 = Gc[(size_t)(e2 & 511u) << 9];
                const float g3 = Gc[(size_t)(e3 & 511u) << 9];
                const float g4 = Gc[(size_t)(e4 & 511u) << 9];
                const float g5 = Gc[(size_t)(e5 & 511u) << 9];
                const float g6 = Gc[(size_t)(e6 & 511u) << 9];
                const float g7 = Gc[(size_t)(e7 & 511u) << 9];
                s0 += (j + 0 < ntot) ? ((e0 & 0x8000u) ? g0 : -g0) : 0.0f;
                s1 += (j + 1 < ntot) ? ((e1 & 0x8000u) ? g1 : -g1) : 0.0f;
                s2 += (j + 2 < ntot) ? ((e2 & 0x8000u) ? g2 : -g2) : 0.0f;
                s3 += (j + 3 < ntot) ? ((e3 & 0x8000u) ? g3 : -g3) : 0.0f;
                s4 += (j + 4 < ntot) ? ((e4 & 0x8000u) ? g4 : -g4) : 0.0f;
                s5 += (j + 5 < ntot) ? ((e5 & 0x8000u) ? g5 : -g5) : 0.0f;
                s6 += (j + 6 < ntot) ? ((e6 & 0x8000u) ? g6 : -g6) : 0.0f;
                s7 += (j + 7 < ntot) ? ((e7 & 0x8000u) ? g7 : -g7) : 0.0f;
            }
            acc += ((s0 + s1) + (s2 + s3)) + ((s4 + s5) + (s6 + s7));
        }

        oldw = hb;
        v = fmaf(dd, v, fmaf(e, acc, cg));
        em *= dd;
    }
}

// ---- Expand: out[t][b][o] = bit b of sp[t][o]. Coalesced float4 stores.
__global__ __launch_bounds__(256) void expand_kernel(
    const unsigned* __restrict__ sp, float* __restrict__ out)
{
    const int tid = threadIdx.x;
    const int t = blockIdx.x >> 3;
    const int bt8 = blockIdx.x & 7;

    __shared__ uint2 sh[NN];
    const uint2* spw = (const uint2*)sp;
    sh[tid]       = spw[((size_t)t * NN + tid) * 8 + bt8];
    sh[tid + 256] = spw[((size_t)t * NN + tid + 256) * 8 + bt8];
    __syncthreads();

    const int b = bt8 * 64 + (tid >> 2);
    const int sub = tid & 3;
    const int rw = (tid >> 2) >> 5;
    const int bit = b & 31;
    float* op = out + (size_t)t * (NN * NN) + (size_t)b * NN;

#pragma unroll 4
    for (int i = 0; i < 32; ++i) {
        const int o = sub * 4 + i * 16;
        const uint2 w0 = sh[o];
        const uint2 w1 = sh[o + 1];
        const uint2 w2 = sh[o + 2];
        const uint2 w3 = sh[o + 3];
        float4 f;
        f.x = (float)(((rw ? w0.y : w0.x) >> bit) & 1u);
        f.y = (float)(((rw ? w1.y : w1.x) >> bit) & 1u);
        f.z = (float)(((rw ? w2.y : w2.x) >> bit) & 1u);
        f.w = (float)(((rw ? w3.y : w3.x) >> bit) & 1u);
        *(float4*)(op + o) = f;
    }
}

// ---- Fallback (tiny ws): round-1 step kernel with direct strided writes.
__global__ __launch_bounds__(256) void snn_step_kernel(
    const float* __restrict__ M, const float* __restrict__ G,
    const float* __restrict__ V0, const float* __restrict__ gs,
    const float* __restrict__ alpha, const float* __restrict__ eta,
    const float* __restrict__ beta, float* __restrict__ out, int T)
{
    const int j = threadIdx.x;
    const int r0 = blockIdx.x * 2;
    const int c0 = 2 * j;
    const float a = alpha[0], e = eta[0], bt = beta[0];
    const float kk = 0.2f, dd = 0.36787944117144233f, Vth = 0.2f;

    float v00 = V0[r0 * NN + c0];
    float v01 = V0[r0 * NN + c0 + 1];
    float v10 = V0[(r0 + 1) * NN + c0];
    float v11 = V0[(r0 + 1) * NN + c0 + 1];
    const float m00 = M[r0 * NN + c0];
    const float m01 = M[r0 * NN + c0 + 1];
    const float m10 = M[(r0 + 1) * NN + c0];
    const float m11 = M[(r0 + 1) * NN + c0 + 1];
    const float gs0 = gs[c0];
    const float gs1 = gs[c0 + 1];

    __shared__ float2 hp[NN];
    float em = 1.0f;
    const float2* Gcol = (const float2*)G + j;

    for (int t = 0; t < T; ++t) {
        const float u00 = kk * (m00 * em + a * v00);
        const float u01 = kk * (m01 * em + a * v01);
        const float u10 = kk * (m10 * em + a * v10);
        const float u11 = kk * (m11 * em + a * v11);

        float* outp = out + (size_t)t * (NN * NN);
        float2 sA = make_float2(u00 > Vth ? 1.f : 0.f, u10 > Vth ? 1.f : 0.f);
        float2 sB = make_float2(u01 > Vth ? 1.f : 0.f, u11 > Vth ? 1.f : 0.f);
        *(float2*)(outp + (size_t)c0 * NN + r0) = sA;
        *(float2*)(outp + (size_t)(c0 + 1) * NN + r0) = sB;

        hp[c0]     = make_float2(u00 > 0.f ? 1.f : 0.f, u10 > 0.f ? 1.f : 0.f);
        hp[c0 + 1] = make_float2(u01 > 0.f ? 1.f : 0.f, u11 > 0.f ? 1.f : 0.f);
        __syncthreads();

        float acc00 = 0.f, acc01 = 0.f, acc10 = 0.f, acc11 = 0.f;
#pragma unroll 8
        for (int bp = 0; bp < NN; ++bp) {
            float2 h = hp[bp];
            float2 g = Gcol[(size_t)bp * 256];
            acc00 = fmaf(h.x, g.x, acc00);
            acc01 = fmaf(h.x, g.y, acc01);
            acc10 = fmaf(h.y, g.x, acc10);
            acc11 = fmaf(h.y, g.y, acc11);
        }

        v00 = dd * v00 + e * (acc00 + bt * gs0);
        v01 = dd * v01 + e * (acc01 + bt * gs1);
        v10 = dd * v10 + e * (acc10 + bt * gs0);
        v11 = dd * v11 + e * (acc11 + bt * gs1);
        em *= dd;
        __syncthreads();
    }
}

extern "C" void kernel_launch(void* const* d_in, const int* in_sizes, int n_in,
                              void* d_out, int out_size, void* d_ws, size_t ws_size,
                              hipStream_t stream)
{
    const float* x     = (const float*)d_in[0];
    const float* W     = (const float*)d_in[1];
    const float* bias  = (const float*)d_in[2];
    const float* alpha = (const float*)d_in[3];
    const float* eta   = (const float*)d_in[4];
    const float* beta  = (const float*)d_in[5];
    const float* P0    = (const float*)d_in[6];
    (void)in_sizes; (void)n_in;

    const int T = out_size / (NN * NN);

    float* ws   = (float*)d_ws;
    float* M    = ws;                          // [512,512] final (relu+bias)
    float* V0   = ws + NN * NN;                // [512,512]
    float* G    = ws + 2 * NN * NN;            // [512,512] = 1 MB
    float* ACC0 = ws + 3 * NN * NN;            // [512,512] = 1 MB
    float* gsv  = ws + 4 * NN * NN;            // [512]
    unsigned* sp = (unsigned*)(gsv + NN);      // [T][512][16] words

    const size_t need_main = ((size_t)4 * NN * NN + NN) * 4 + (size_t)T * NN * 16 * 4;

    hipLaunchKernelGGL(gemm64_kernel, dim3(192), dim3(256), 0, stream,
                       x, W, P0, bias, M, V0, G);
    hipLaunchKernelGGL(colsum_kernel, dim3(8), dim3(256), 0, stream, G, gsv);

    if (ws_size >= need_main) {
        hipLaunchKernelGGL(acc0_kernel, dim3(256), dim3(256), 0, stream,
                           M, V0, G, alpha, ACC0);
        hipLaunchKernelGGL(snn_bits7_kernel, dim3(NN), dim3(512), 0, stream,
                           M, G, V0, ACC0, gsv, alpha, eta, beta, sp, T);
        hipLaunchKernelGGL(expand_kernel, dim3(T * 8), dim3(256), 0, stream,
                           sp, (float*)d_out);
    } else {
        hipLaunchKernelGGL(snn_step_kernel, dim3(256), dim3(256), 0, stream,
                           M, G, V0, gsv, alpha, eta, beta, (float*)d_out, T);
    }
}

// Round 14
// 126.884 us; speedup vs baseline: 1.2761x; 1.0337x over previous
//
#include <hip/hip_runtime.h>

// B = IN = OUT = 512; T from out_size.
// v_t = P_t @ x^T [OUT,B]; G = x@x^T [B,B]
//   u = k*(M*e^{-t} + a*v);  h = (u>0);  s = (u>0.2)
//   v' = d*v + e*(h@G + bt*colsum(G))
// Round-14:
//  gemm_splitk: grid 768 (3 blocks/CU, 3 waves/SIMD), 64x64 tiles, 4x4 micro,
//    split-K x4 -> latency hidden (round-13's grid-192 full-K ran 1 wave/SIMD,
//    ~3x above its LDS-BW floor). combine kernel sums partials pairwise +
//    fuses bias/relu. 13 rounds of reassociation evidence -> split-K safe.
//  acc0+colsum fused (rb==0 blocks also compute gs). snn: 16-wide named-
//    scalar apply (halves serialized L2 round-trips in transient steps).

#define NN 512

// ---- Split-K GEMM: grid 768 = 3 outputs x 4 K-quarters x 64 tiles(64x64).
// out 0: W·x^T; out 1: P0·x^T; out 2: x·x^T. Raw partials (no bias/relu).
__global__ __launch_bounds__(256) void gemm_splitk_kernel(
    const float* __restrict__ x, const float* __restrict__ W,
    const float* __restrict__ P0, float* __restrict__ part)
{
    const int tid = threadIdx.x;
    const int bid = blockIdx.x;          // 0..767
    const int out = bid >> 8;            // 0..2
    const int rem = bid & 255;
    const int kq = rem >> 6;             // 0..3
    const int tl = rem & 63;
    const int rb = (tl >> 3) << 6;
    const int cb = (tl & 7) << 6;
    const int kbase = kq << 7;           // 0,128,256,384

    const float* A = ((out == 0) ? W : (out == 1) ? P0 : x) + (size_t)rb * NN;
    const float* Bx = x + (size_t)cb * NN;
    float* D = part + (size_t)(out * 4 + kq) * NN * NN;

    const int tx = tid & 15;             // cols 4tx..4tx+3
    const int ty = tid >> 4;             // rows 4ty..4ty+3

    __shared__ float At[32][68];
    __shared__ float Bt[32][68];

    const int lr = tid >> 2;             // 0..63
    const int lk = (tid & 3) << 3;       // 0,8,16,24

    float acc[4][4] = {{0.f,0.f,0.f,0.f},{0.f,0.f,0.f,0.f},
                       {0.f,0.f,0.f,0.f},{0.f,0.f,0.f,0.f}};

    float4 a0 = *(const float4*)(A + (size_t)lr * NN + kbase + lk);
    float4 a1 = *(const float4*)(A + (size_t)lr * NN + kbase + lk + 4);
    float4 b0 = *(const float4*)(Bx + (size_t)lr * NN + kbase + lk);
    float4 b1 = *(const float4*)(Bx + (size_t)lr * NN + kbase + lk + 4);

    for (int c = 0; c < 4; ++c) {
        __syncthreads();
        At[lk + 0][lr] = a0.x; At[lk + 1][lr] = a0.y;
        At[lk + 2][lr] = a0.z; At[lk + 3][lr] = a0.w;
        At[lk + 4][lr] = a1.x; At[lk + 5][lr] = a1.y;
        At[lk + 6][lr] = a1.z; At[lk + 7][lr] = a1.w;
        Bt[lk + 0][lr] = b0.x; Bt[lk + 1][lr] = b0.y;
        Bt[lk + 2][lr] = b0.z; Bt[lk + 3][lr] = b0.w;
        Bt[lk + 4][lr] = b1.x; Bt[lk + 5][lr] = b1.y;
        Bt[lk + 6][lr] = b1.z; Bt[lk + 7][lr] = b1.w;
        __syncthreads();

        if (c < 3) {
            const int k0 = kbase + ((c + 1) << 5);
            a0 = *(const float4*)(A + (size_t)lr * NN + k0 + lk);
            a1 = *(const float4*)(A + (size_t)lr * NN + k0 + lk + 4);
            b0 = *(const float4*)(Bx + (size_t)lr * NN + k0 + lk);
            b1 = *(const float4*)(Bx + (size_t)lr * NN + k0 + lk + 4);
        }

#pragma unroll
        for (int k = 0; k < 32; ++k) {
            const float4 av = *(const float4*)&At[k][4 * ty];
            const float4 bv = *(const float4*)&Bt[k][4 * tx];
            const float avs[4] = {av.x, av.y, av.z, av.w};
            const float bvs[4] = {bv.x, bv.y, bv.z, bv.w};
#pragma unroll
            for (int i = 0; i < 4; ++i)
#pragma unroll
                for (int j = 0; j < 4; ++j)
                    acc[i][j] = fmaf(avs[i], bvs[j], acc[i][j]);
        }
    }

#pragma unroll
    for (int i = 0; i < 4; ++i) {
        const int r = rb + 4 * ty + i;
        *(float4*)(D + (size_t)r * NN + cb + 4 * tx) =
            make_float4(acc[i][0], acc[i][1], acc[i][2], acc[i][3]);
    }
}

// ---- combine: finals from partials, pairwise sum; bias+relu for M.
// grid 768 x 256 thr; one float4 per thread (3 MB total).
__global__ __launch_bounds__(256) void combine_kernel(
    const float* __restrict__ part, const float* __restrict__ bias,
    float* __restrict__ M, float* __restrict__ V0, float* __restrict__ G)
{
    const int idx = blockIdx.x * 256 + threadIdx.x;   // 0..196607
    const int out = idx >> 16;                        // 0..2
    const int io = idx & 65535;
    const float4* p = (const float4*)(part + (size_t)out * 4 * NN * NN);
    const float4 p0 = p[io];
    const float4 p1 = p[io + 65536];
    const float4 p2 = p[io + 131072];
    const float4 p3 = p[io + 196608];
    float4 s;
    s.x = (p0.x + p1.x) + (p2.x + p3.x);
    s.y = (p0.y + p1.y) + (p2.y + p3.y);
    s.z = (p0.z + p1.z) + (p2.z + p3.z);
    s.w = (p0.w + p1.w) + (p2.w + p3.w);
    if (out == 0) {
        const float bb = bias[io >> 7];
        s.x = fmaxf(s.x + bb, 0.f); s.y = fmaxf(s.y + bb, 0.f);
        s.z = fmaxf(s.z + bb, 0.f); s.w = fmaxf(s.w + bb, 0.f);
        ((float4*)M)[io] = s;
    } else if (out == 1) {
        ((float4*)V0)[io] = s;
    } else {
        ((float4*)G)[io] = s;
    }
}

// ---- acc0 + colsum: ACC0 = H0@G, H0 = (kk*fmaf(a,V0,M) > 0).
// 32x32 tiles, grid 256. Blocks with rb==0 additionally compute gs[cb..cb+31].
__global__ __launch_bounds__(256) void acc0cs_kernel(
    const float* __restrict__ M, const float* __restrict__ V0,
    const float* __restrict__ G, const float* __restrict__ alpha,
    float* __restrict__ ACC0, float* __restrict__ gs)
{
    const int tid = threadIdx.x;
    const int rb = (blockIdx.x >> 4) << 5;
    const int cb = (blockIdx.x & 15) << 5;
    const float a = alpha[0];
    const float kk = 0.2f;

    __shared__ float Ht[32][36];
    __shared__ float Bt[32][36];

    const int tx = tid & 15;
    const int ty = tid >> 4;
    const int lr = tid >> 3;
    const int lk = (tid & 7) << 2;

    float acc[2][2] = {{0.f, 0.f}, {0.f, 0.f}};

    for (int k0 = 0; k0 < NN; k0 += 32) {
        const float4 mv = *(const float4*)(M + (size_t)(rb + lr) * NN + k0 + lk);
        const float4 vv = *(const float4*)(V0 + (size_t)(rb + lr) * NN + k0 + lk);
        const float4 gv = *(const float4*)(G + (size_t)(k0 + lr) * NN + cb + lk);
        __syncthreads();
        Ht[lk + 0][lr] = (kk * fmaf(a, vv.x, mv.x) > 0.f) ? 1.f : 0.f;
        Ht[lk + 1][lr] = (kk * fmaf(a, vv.y, mv.y) > 0.f) ? 1.f : 0.f;
        Ht[lk + 2][lr] = (kk * fmaf(a, vv.z, mv.z) > 0.f) ? 1.f : 0.f;
        Ht[lk + 3][lr] = (kk * fmaf(a, vv.w, mv.w) > 0.f) ? 1.f : 0.f;
        Bt[lr][lk + 0] = gv.x; Bt[lr][lk + 1] = gv.y;
        Bt[lr][lk + 2] = gv.z; Bt[lr][lk + 3] = gv.w;
        __syncthreads();

#pragma unroll
        for (int k = 0; k < 32; ++k) {
            const float2 av = *(const float2*)&Ht[k][2 * ty];
            const float2 bv = *(const float2*)&Bt[k][2 * tx];
            acc[0][0] = fmaf(av.x, bv.x, acc[0][0]);
            acc[0][1] = fmaf(av.x, bv.y, acc[0][1]);
            acc[1][0] = fmaf(av.y, bv.x, acc[1][0]);
            acc[1][1] = fmaf(av.y, bv.y, acc[1][1]);
        }
    }

#pragma unroll
    for (int i = 0; i < 2; ++i) {
        *(float2*)(ACC0 + (size_t)(rb + 2 * ty + i) * NN + cb + 2 * tx) =
            make_float2(acc[i][0], acc[i][1]);
    }

    // fused colsum: 16 blocks (rb==0) cover all 512 columns
    if (rb == 0) {
        __syncthreads();                  // Ht reuse safety
        float* red = (float*)Ht;
        const int c = cb + (tid & 31);
        const int g = tid >> 5;           // 0..7: rows 64g..64g+63
        float s = 0.f;
#pragma unroll 8
        for (int bp = 64 * g; bp < 64 * g + 64; ++bp)
            s += G[(size_t)bp * NN + c];
        red[g * 32 + (tid & 31)] = s;
        __syncthreads();
        if (g == 0) {
            const int cc = tid & 31;
            const float tot =
                ((red[cc] + red[32 + cc]) + (red[64 + cc] + red[96 + cc])) +
                ((red[128 + cc] + red[160 + cc]) + (red[192 + cc] + red[224 + cc]));
            gs[c] = tot;
        }
    }
}

// ---- Main recurrence: 512 blocks x 512 threads. Thread owns col c = tid.
// t=0: acc := ACC0. t>=1: frozen = 1 barrier; transient = list build +
// 16-wide named-scalar apply (16 independent G loads per trip).
__global__ __launch_bounds__(512, 4) void snn_bits8_kernel(
    const float* __restrict__ M, const float* __restrict__ G,
    const float* __restrict__ V0, const float* __restrict__ ACC0,
    const float* __restrict__ gs, const float* __restrict__ alpha,
    const float* __restrict__ eta, const float* __restrict__ beta,
    unsigned* __restrict__ sp, int T)
{
    const int tid = threadIdx.x;
    const int w = tid >> 6;
    const int lane = tid & 63;
    const int r = blockIdx.x;

    __shared__ unsigned long long lflag[2];
    __shared__ int wcnt[8];
    __shared__ unsigned short list[544] __attribute__((aligned(16)));

    const float a = alpha[0], e = eta[0], bt = beta[0];
    const float kk = 0.2f;
    const float dd = 0.36787944117144233f;   // exp(-1)
    const float Vth = 0.2f;

    const size_t rc = (size_t)r * NN + tid;
    const float m = M[rc];
    float v = V0[rc];
    const float cg = e * bt * gs[tid];
    const float* Gc = G + tid;

    float acc;
    float em;
    unsigned long long oldw;

    // ---- t = 0: bulk apply from ACC0
    {
        const float u = kk * fmaf(a, v, m * 1.0f);
        const unsigned long long hb = __ballot(u > 0.f);
        const unsigned long long sb = __ballot(u > Vth);
        if (lane == 0)
            *(unsigned long long*)(sp + (size_t)r * 16 + 2 * w) = sb;
        oldw = hb;
        acc = ACC0[rc];
        v = fmaf(dd, v, fmaf(e, acc, cg));
        em = dd;
    }

    for (int t = 1; t < T; ++t) {
        const float u = kk * fmaf(a, v, m * em);
        const unsigned long long hb = __ballot(u > 0.f);
        const unsigned long long sb = __ballot(u > Vth);
        const unsigned long long xw = hb ^ oldw;
        const int p = t & 1;
        if (lane == 0) {
            ((unsigned char*)&lflag[p])[w] = (xw != 0ull) ? (unsigned char)1 : (unsigned char)0;
            wcnt[w] = (int)__popcll(xw);
            *(unsigned long long*)(sp + ((size_t)t * NN + r) * 16 + 2 * w) = sb;
        }
        __syncthreads();   // B1

        if (lflag[p] != 0ull) {
            const int c0 = wcnt[0], c1 = wcnt[1], c2 = wcnt[2], c3 = wcnt[3];
            const int c4 = wcnt[4], c5 = wcnt[5], c6 = wcnt[6], c7 = wcnt[7];
            const int ntot = ((c0 + c1) + (c2 + c3)) + ((c4 + c5) + (c6 + c7));
            int base = 0;
            if (w > 0) base += c0;
            if (w > 1) base += c1;
            if (w > 2) base += c2;
            if (w > 3) base += c3;
            if (w > 4) base += c4;
            if (w > 5) base += c5;
            if (w > 6) base += c6;

            if ((xw >> lane) & 1ull) {
                const int pos = (int)__popcll(xw & ((1ull << lane) - 1ull));
                const unsigned row = (unsigned)((w << 6) + lane);
                const unsigned sgn = (unsigned)((hb >> lane) & 1ull) << 15;
                list[base + pos] = (unsigned short)(row | sgn);
            }
            __syncthreads();   // B2: list ready

            float s0 = 0.f, s1 = 0.f, s2 = 0.f, s3 = 0.f;
            float s4 = 0.f, s5 = 0.f, s6 = 0.f, s7 = 0.f;
            for (int j = 0; j < ntot; j += 16) {
                const uint4 leA = *(const uint4*)(list + j);
                const uint4 leB = *(const uint4*)(list + j + 8);
                const unsigned e0 = leA.x & 0xFFFFu,  e1 = leA.x >> 16;
                const unsigned e2 = leA.y & 0xFFFFu,  e3 = leA.y >> 16;
                const unsigned e4 = leA.z & 0xFFFFu,  e5 = leA.z >> 16;
                const unsigned e6 = leA.w & 0xFFFFu,  e7 = leA.w >> 16;
                const unsigned e8 = leB.x & 0xFFFFu,  e9 = leB.x >> 16;
                const unsigned ea = leB.y & 0xFFFFu,  eb = leB.y >> 16;
                const unsigned ec = leB.z & 0xFFFFu,  ed = leB.z >> 16;
                const unsigned ee = leB.w & 0xFFFFu,  ef = leB.w >> 16;
                const float g0 = Gc[(size_t)(e0 & 511u) << 9];
                const float g1 = Gc[(size_t)(e1 & 511u) << 9];
                const float g2 = Gc[(size_t)(e2 & 511u) << 9];
                const float g3 = Gc[(size_t)(e3 & 511u) << 9];
                const float g4 = Gc[(size_t)(e4 & 511u) << 9];
                const float g5 = Gc[(size_t)(e5 & 511u) << 9];
                const float g6 = Gc[(size_t)(e6 & 511u) << 9];
                const float g7 = Gc[(size_t)(e7 & 511u) << 9];
                const float g8 = Gc[(size_t)(e8 & 511u) << 9];
                const float g9 = Gc[(size_t)(e9 & 511u) << 9];
                const float ga = Gc[(size_t)(ea & 511u) << 9];
                const float gb = Gc[(size_t)(eb & 511u) << 9];
                const float gc2 = Gc[(size_t)(ec & 511u) << 9];
                const float gd = Gc[(size_t)(ed & 511u) << 9];
                const float ge = Gc[(size_t)(ee & 511u) << 9];
                const float gf = Gc[(size_t)(ef & 511u) << 9];
                s0 += (j + 0  < ntot) ? ((e0 & 0x8000u) ? g0 : -g0) : 0.0f;
                s1 += (j + 1  < ntot) ? ((e1 & 0x8000u) ? g1 : -g1) : 0.0f;
                s2 += (j + 2  < ntot) ? ((e2 & 0x8000u) ? g2 : -g2) : 0.0f;
                s3 += (j + 3  < ntot) ? ((e3 & 0x8000u) ? g3 : -g3) : 0.0f;
                s4 += (j + 4  < ntot) ? ((e4 & 0x8000u) ? g4 : -g4) : 0.0f;
                s5 += (j + 5  < ntot) ? ((e5 & 0x8000u) ? g5 : -g5) : 0.0f;
                s6 += (j + 6  < ntot) ? ((e6 & 0x8000u) ? g6 : -g6) : 0.0f;
                s7 += (j + 7  < ntot) ? ((e7 & 0x8000u) ? g7 : -g7) : 0.0f;
                s0 += (j + 8  < ntot) ? ((e8 & 0x8000u) ? g8 : -g8) : 0.0f;
                s1 += (j + 9  < ntot) ? ((e9 & 0x8000u) ? g9 : -g9) : 0.0f;
                s2 += (j + 10 < ntot) ? ((ea & 0x8000u) ? ga : -ga) : 0.0f;
                s3 += (j + 11 < ntot) ? ((eb & 0x8000u) ? gb : -gb) : 0.0f;
                s4 += (j + 12 < ntot) ? ((ec & 0x8000u) ? gc2 : -gc2) : 0.0f;
                s5 += (j + 13 < ntot) ? ((ed & 0x8000u) ? gd : -gd) : 0.0f;
                s6 += (j + 14 < ntot) ? ((ee & 0x8000u) ? ge : -ge) : 0.0f;
                s7 += (j + 15 < ntot) ? ((ef & 0x8000u) ? gf : -gf) : 0.0f;
            }
            acc += ((s0 + s1) + (s2 + s3)) + ((s4 + s5) + (s6 + s7));
        }

        oldw = hb;
        v = fmaf(dd, v, fmaf(e, acc, cg));
        em *= dd;
    }
}

// ---- Expand: out[t][b][o] = bit b of sp[t][o]. Coalesced float4 stores.
__global__ __launch_bounds__(256) void expand_kernel(
    const unsigned* __restrict__ sp, float* __restrict__ out)
{
    const int tid = threadIdx.x;
    const int t = blockIdx.x >> 3;
    const int bt8 = blockIdx.x & 7;

    __shared__ uint2 sh[NN];
    const uint2* spw = (const uint2*)sp;
    sh[tid]       = spw[((size_t)t * NN + tid) * 8 + bt8];
    sh[tid + 256] = spw[((size_t)t * NN + tid + 256) * 8 + bt8];
    __syncthreads();

    const int b = bt8 * 64 + (tid >> 2);
    const int sub = tid & 3;
    const int rw = (tid >> 2) >> 5;
    const int bit = b & 31;
    float* op = out + (size_t)t * (NN * NN) + (size_t)b * NN;

#pragma unroll 4
    for (int i = 0; i < 32; ++i) {
        const int o = sub * 4 + i * 16;
        const uint2 w0 = sh[o];
        const uint2 w1 = sh[o + 1];
        const uint2 w2 = sh[o + 2];
        const uint2 w3 = sh[o + 3];
        float4 f;
        f.x = (float)(((rw ? w0.y : w0.x) >> bit) & 1u);
        f.y = (float)(((rw ? w1.y : w1.x) >> bit) & 1u);
        f.z = (float)(((rw ? w2.y : w2.x) >> bit) & 1u);
        f.w = (float)(((rw ? w3.y : w3.x) >> bit) & 1u);
        *(float4*)(op + o) = f;
    }
}

// ================= Fallback path (tiny ws): round-13 full-K gemm + colsum +
// round-1 step kernel.
__global__ __launch_bounds__(256) void gemm64_kernel(
    const float* __restrict__ x, const float* __restrict__ W,
    const float* __restrict__ P0, const float* __restrict__ bias,
    float* __restrict__ M, float* __restrict__ V0, float* __restrict__ G)
{
    const int tid = threadIdx.x;
    const int bid = blockIdx.x;
    const int out = bid >> 6;
    const int tl = bid & 63;
    const int rb = (tl >> 3) << 6;
    const int cb = (tl & 7) << 6;

    const float* A = ((out == 0) ? W : (out == 1) ? P0 : x) + (size_t)rb * NN;
    const float* Bx = x + (size_t)cb * NN;
    float* D = (out == 0) ? M : (out == 1) ? V0 : G;

    const int tx = tid & 15;
    const int ty = tid >> 4;

    __shared__ float At[32][68];
    __shared__ float Bt[32][68];

    const int lr = tid >> 2;
    const int lk = (tid & 3) << 3;

    float acc[4][4] = {{0.f,0.f,0.f,0.f},{0.f,0.f,0.f,0.f},
                       {0.f,0.f,0.f,0.f},{0.f,0.f,0.f,0.f}};

    float4 a0 = *(const float4*)(A + (size_t)lr * NN + lk);
    float4 a1 = *(const float4*)(A + (size_t)lr * NN + lk + 4);
    float4 b0 = *(const float4*)(Bx + (size_t)lr * NN + lk);
    float4 b1 = *(const float4*)(Bx + (size_t)lr * NN + lk + 4);

    for (int c = 0; c < 16; ++c) {
        __syncthreads();
        At[lk + 0][lr] = a0.x; At[lk + 1][lr] = a0.y;
        At[lk + 2][lr] = a0.z; At[lk + 3][lr] = a0.w;
        At[lk + 4][lr] = a1.x; At[lk + 5][lr] = a1.y;
        At[lk + 6][lr] = a1.z; At[lk + 7][lr] = a1.w;
        Bt[lk + 0][lr] = b0.x; Bt[lk + 1][lr] = b0.y;
        Bt[lk + 2][lr] = b0.z; Bt[lk + 3][lr] = b0.w;
        Bt[lk + 4][lr] = b1.x; Bt[lk + 5][lr] = b1.y;
        Bt[lk + 6][lr] = b1.z; Bt[lk + 7][lr] = b1.w;
        __syncthreads();

        if (c < 15) {
            const int k0 = (c + 1) << 5;
            a0 = *(const float4*)(A + (size_t)lr * NN + k0 + lk);
            a1 = *(const float4*)(A + (size_t)lr * NN + k0 + lk + 4);
            b0 = *(const float4*)(Bx + (size_t)lr * NN + k0 + lk);
            b1 = *(const float4*)(Bx + (size_t)lr * NN + k0 + lk + 4);
        }

#pragma unroll
        for (int k = 0; k < 32; ++k) {
            const float4 av = *(const float4*)&At[k][4 * ty];
            const float4 bv = *(const float4*)&Bt[k][4 * tx];
            const float avs[4] = {av.x, av.y, av.z, av.w};
            const float bvs[4] = {bv.x, bv.y, bv.z, bv.w};
#pragma unroll
            for (int i = 0; i < 4; ++i)
#pragma unroll
                for (int j = 0; j < 4; ++j)
                    acc[i][j] = fmaf(avs[i], bvs[j], acc[i][j]);
        }
    }

#pragma unroll
    for (int i = 0; i < 4; ++i) {
        const int r = rb + 4 * ty + i;
        float4 o = make_float4(acc[i][0], acc[i][1], acc[i][2], acc[i][3]);
        if (out == 0) {
            const float bb = bias[r];
            o.x = fmaxf(o.x + bb, 0.f); o.y = fmaxf(o.y + bb, 0.f);
            o.z = fmaxf(o.z + bb, 0.f); o.w = fmaxf(o.w + bb, 0.f);
        }
        *(float4*)(D + (size_t)r * NN + cb + 4 * tx) = o;
    }
}

__global__ __launch_bounds__(256) void colsum_kernel(
    const float* __restrict__ G, float* __restrict__ gs)
{
    __shared__ float red[4][64];
    const int tid = threadIdx.x;
    const int c = (blockIdx.x << 6) + (tid & 63);
    const int g = tid >> 6;
    float s = 0.f;
#pragma unroll 8
    for (int bp = 128 * g; bp < 128 * g + 128; ++bp) s += G[(size_t)bp * NN + c];
    if (g > 0) red[g][tid & 63] = s;
    __syncthreads();
    if (g == 0) gs[c] = ((s + red[1][tid & 63]) + red[2][tid & 63]) + red[3][tid & 63];
}

__global__ __launch_bounds__(256) void snn_step_kernel(
    const float* __restrict__ M, const float* __restrict__ G,
    const float* __restrict__ V0, const float* __restrict__ gs,
    const float* __restrict__ alpha, const float* __restrict__ eta,
    const float* __restrict__ beta, float* __restrict__ out, int T)
{
    const int j = threadIdx.x;
    const int r0 = blockIdx.x * 2;
    const int c0 = 2 * j;
    const float a = alpha[0], e = eta[0], bt = beta[0];
    const float kk = 0.2f, dd = 0.36787944117144233f, Vth = 0.2f;

    float v00 = V0[r0 * NN + c0];
    float v01 = V0[r0 * NN + c0 + 1];
    float v10 = V0[(r0 + 1) * NN + c0];
    float v11 = V0[(r0 + 1) * NN + c0 + 1];
    const float m00 = M[r0 * NN + c0];
    const float m01 = M[r0 * NN + c0 + 1];
    const float m10 = M[(r0 + 1) * NN + c0];
    const float m11 = M[(r0 + 1) * NN + c0 + 1];
    const float gs0 = gs[c0];
    const float gs1 = gs[c0 + 1];

    __shared__ float2 hp[NN];
    float em = 1.0f;
    const float2* Gcol = (const float2*)G + j;

    for (int t = 0; t < T; ++t) {
        const float u00 = kk * (m00 * em + a * v00);
        const float u01 = kk * (m01 * em + a * v01);
        const float u10 = kk * (m10 * em + a * v10);
        const float u11 = kk * (m11 * em + a * v11);

        float* outp = out + (size_t)t * (NN * NN);
        float2 sA = make_float2(u00 > Vth ? 1.f : 0.f, u10 > Vth ? 1.f : 0.f);
        float2 sB = make_float2(u01 > Vth ? 1.f : 0.f, u11 > Vth ? 1.f : 0.f);
        *(float2*)(outp + (size_t)c0 * NN + r0) = sA;
        *(float2*)(outp + (size_t)(c0 + 1) * NN + r0) = sB;

        hp[c0]     = make_float2(u00 > 0.f ? 1.f : 0.f, u10 > 0.f ? 1.f : 0.f);
        hp[c0 + 1] = make_float2(u01 > 0.f ? 1.f : 0.f, u11 > 0.f ? 1.f : 0.f);
        __syncthreads();

        float acc00 = 0.f, acc01 = 0.f, acc10 = 0.f, acc11 = 0.f;
#pragma unroll 8
        for (int bp = 0; bp < NN; ++bp) {
            float2 h = hp[bp];
            float2 g = Gcol[(size_t)bp * 256];
            acc00 = fmaf(h.x, g.x, acc00);
            acc01 = fmaf(h.x, g.y, acc01);
            acc10 = fmaf(h.y, g.x, acc10);
            acc11 = fmaf(h.y, g.y, acc11);
        }

        v00 = dd * v00 + e * (acc00 + bt * gs0);
        v01 = dd * v01 + e * (acc01 + bt * gs1);
        v10 = dd * v10 + e * (acc10 + bt * gs0);
        v11 = dd * v11 + e * (acc11 + bt * gs1);
        em *= dd;
        __syncthreads();
    }
}

extern "C" void kernel_launch(void* const* d_in, const int* in_sizes, int n_in,
                              void* d_out, int out_size, void* d_ws, size_t ws_size,
                              hipStream_t stream)
{
    const float* x     = (const float*)d_in[0];
    const float* W     = (const float*)d_in[1];
    const float* bias  = (const float*)d_in[2];
    const float* alpha = (const float*)d_in[3];
    const float* eta   = (const float*)d_in[4];
    const float* beta  = (const float*)d_in[5];
    const float* P0    = (const float*)d_in[6];
    (void)in_sizes; (void)n_in;

    const int T = out_size / (NN * NN);

    float* ws   = (float*)d_ws;
    float* part = ws;                          // 12 x [512,512] split partials
    float* M    = ws + 12 * NN * NN;           // finals
    float* V0   = ws + 13 * NN * NN;
    float* G    = ws + 14 * NN * NN;
    float* ACC0 = ws + 15 * NN * NN;
    float* gsv  = ws + 16 * NN * NN;           // [512]
    unsigned* sp = (unsigned*)(gsv + NN);      // [T][512][16] words

    const size_t need_main = ((size_t)16 * NN * NN + NN) * 4 + (size_t)T * NN * 16 * 4;

    if (ws_size >= need_main) {
        hipLaunchKernelGGL(gemm_splitk_kernel, dim3(768), dim3(256), 0, stream,
                           x, W, P0, part);
        hipLaunchKernelGGL(combine_kernel, dim3(768), dim3(256), 0, stream,
                           part, bias, M, V0, G);
        hipLaunchKernelGGL(acc0cs_kernel, dim3(256), dim3(256), 0, stream,
                           M, V0, G, alpha, ACC0, gsv);
        hipLaunchKernelGGL(snn_bits8_kernel, dim3(NN), dim3(512), 0, stream,
                           M, G, V0, ACC0, gsv, alpha, eta, beta, sp, T);
        hipLaunchKernelGGL(expand_kernel, dim3(T * 8), dim3(256), 0, stream,
                           sp, (float*)d_out);
    } else {
        float* Mf  = ws;
        float* V0f = ws + NN * NN;
        float* Gf  = ws + 2 * NN * NN;
        float* gs2 = ws + 3 * NN * NN;
        hipLaunchKernelGGL(gemm64_kernel, dim3(192), dim3(256), 0, stream,
                           x, W, P0, bias, Mf, V0f, Gf);
        hipLaunchKernelGGL(colsum_kernel, dim3(8), dim3(256), 0, stream, Gf, gs2);
        hipLaunchKernelGGL(snn_step_kernel, dim3(256), dim3(256), 0, stream,
                           Mf, Gf, V0f, gs2, alpha, eta, beta, (float*)d_out, T);
    }
}

// Round 15
// 116.399 us; speedup vs baseline: 1.3910x; 1.0901x over previous
//
#include <hip/hip_runtime.h>

// B = IN = OUT = 512; T from out_size.
// v_t = P_t @ x^T [OUT,B]; G = x@x^T [B,B]
//   u = k*(M*e^{-t} + a*v);  h = (u>0);  s = (u>0.2)
//   v' = d*v + e*(h@G + bt*colsum(G))
// Round-15: round-14 prologue (split-K gemm + combine + fused acc0cs, ~16us
// faster than round-13's) + round-13 snn_bits7 verbatim (8-wide named-scalar
// apply, 42.3us measured; round-14's 16-wide regressed to 54.5 -- VGPR=24
// shows the compiler re-rolled the wider batch; 8-wide is the sweet spot).

#define NN 512

// ---- Split-K GEMM: grid 768 = 3 outputs x 4 K-quarters x 64 tiles(64x64).
__global__ __launch_bounds__(256) void gemm_splitk_kernel(
    const float* __restrict__ x, const float* __restrict__ W,
    const float* __restrict__ P0, float* __restrict__ part)
{
    const int tid = threadIdx.x;
    const int bid = blockIdx.x;          // 0..767
    const int out = bid >> 8;            // 0..2
    const int rem = bid & 255;
    const int kq = rem >> 6;             // 0..3
    const int tl = rem & 63;
    const int rb = (tl >> 3) << 6;
    const int cb = (tl & 7) << 6;
    const int kbase = kq << 7;           // 0,128,256,384

    const float* A = ((out == 0) ? W : (out == 1) ? P0 : x) + (size_t)rb * NN;
    const float* Bx = x + (size_t)cb * NN;
    float* D = part + (size_t)(out * 4 + kq) * NN * NN;

    const int tx = tid & 15;
    const int ty = tid >> 4;

    __shared__ float At[32][68];
    __shared__ float Bt[32][68];

    const int lr = tid >> 2;
    const int lk = (tid & 3) << 3;

    float acc[4][4] = {{0.f,0.f,0.f,0.f},{0.f,0.f,0.f,0.f},
                       {0.f,0.f,0.f,0.f},{0.f,0.f,0.f,0.f}};

    float4 a0 = *(const float4*)(A + (size_t)lr * NN + kbase + lk);
    float4 a1 = *(const float4*)(A + (size_t)lr * NN + kbase + lk + 4);
    float4 b0 = *(const float4*)(Bx + (size_t)lr * NN + kbase + lk);
    float4 b1 = *(const float4*)(Bx + (size_t)lr * NN + kbase + lk + 4);

    for (int c = 0; c < 4; ++c) {
        __syncthreads();
        At[lk + 0][lr] = a0.x; At[lk + 1][lr] = a0.y;
        At[lk + 2][lr] = a0.z; At[lk + 3][lr] = a0.w;
        At[lk + 4][lr] = a1.x; At[lk + 5][lr] = a1.y;
        At[lk + 6][lr] = a1.z; At[lk + 7][lr] = a1.w;
        Bt[lk + 0][lr] = b0.x; Bt[lk + 1][lr] = b0.y;
        Bt[lk + 2][lr] = b0.z; Bt[lk + 3][lr] = b0.w;
        Bt[lk + 4][lr] = b1.x; Bt[lk + 5][lr] = b1.y;
        Bt[lk + 6][lr] = b1.z; Bt[lk + 7][lr] = b1.w;
        __syncthreads();

        if (c < 3) {
            const int k0 = kbase + ((c + 1) << 5);
            a0 = *(const float4*)(A + (size_t)lr * NN + k0 + lk);
            a1 = *(const float4*)(A + (size_t)lr * NN + k0 + lk + 4);
            b0 = *(const float4*)(Bx + (size_t)lr * NN + k0 + lk);
            b1 = *(const float4*)(Bx + (size_t)lr * NN + k0 + lk + 4);
        }

#pragma unroll
        for (int k = 0; k < 32; ++k) {
            const float4 av = *(const float4*)&At[k][4 * ty];
            const float4 bv = *(const float4*)&Bt[k][4 * tx];
            const float avs[4] = {av.x, av.y, av.z, av.w};
            const float bvs[4] = {bv.x, bv.y, bv.z, bv.w};
#pragma unroll
            for (int i = 0; i < 4; ++i)
#pragma unroll
                for (int j = 0; j < 4; ++j)
                    acc[i][j] = fmaf(avs[i], bvs[j], acc[i][j]);
        }
    }

#pragma unroll
    for (int i = 0; i < 4; ++i) {
        const int r = rb + 4 * ty + i;
        *(float4*)(D + (size_t)r * NN + cb + 4 * tx) =
            make_float4(acc[i][0], acc[i][1], acc[i][2], acc[i][3]);
    }
}

// ---- combine: finals from partials, pairwise sum; bias+relu for M.
__global__ __launch_bounds__(256) void combine_kernel(
    const float* __restrict__ part, const float* __restrict__ bias,
    float* __restrict__ M, float* __restrict__ V0, float* __restrict__ G)
{
    const int idx = blockIdx.x * 256 + threadIdx.x;   // 0..196607
    const int out = idx >> 16;                        // 0..2
    const int io = idx & 65535;
    const float4* p = (const float4*)(part + (size_t)out * 4 * NN * NN);
    const float4 p0 = p[io];
    const float4 p1 = p[io + 65536];
    const float4 p2 = p[io + 131072];
    const float4 p3 = p[io + 196608];
    float4 s;
    s.x = (p0.x + p1.x) + (p2.x + p3.x);
    s.y = (p0.y + p1.y) + (p2.y + p3.y);
    s.z = (p0.z + p1.z) + (p2.z + p3.z);
    s.w = (p0.w + p1.w) + (p2.w + p3.w);
    if (out == 0) {
        const float bb = bias[io >> 7];
        s.x = fmaxf(s.x + bb, 0.f); s.y = fmaxf(s.y + bb, 0.f);
        s.z = fmaxf(s.z + bb, 0.f); s.w = fmaxf(s.w + bb, 0.f);
        ((float4*)M)[io] = s;
    } else if (out == 1) {
        ((float4*)V0)[io] = s;
    } else {
        ((float4*)G)[io] = s;
    }
}

// ---- acc0 + colsum: ACC0 = H0@G, H0 = (kk*fmaf(a,V0,M) > 0).
__global__ __launch_bounds__(256) void acc0cs_kernel(
    const float* __restrict__ M, const float* __restrict__ V0,
    const float* __restrict__ G, const float* __restrict__ alpha,
    float* __restrict__ ACC0, float* __restrict__ gs)
{
    const int tid = threadIdx.x;
    const int rb = (blockIdx.x >> 4) << 5;
    const int cb = (blockIdx.x & 15) << 5;
    const float a = alpha[0];
    const float kk = 0.2f;

    __shared__ float Ht[32][36];
    __shared__ float Bt[32][36];

    const int tx = tid & 15;
    const int ty = tid >> 4;
    const int lr = tid >> 3;
    const int lk = (tid & 7) << 2;

    float acc[2][2] = {{0.f, 0.f}, {0.f, 0.f}};

    for (int k0 = 0; k0 < NN; k0 += 32) {
        const float4 mv = *(const float4*)(M + (size_t)(rb + lr) * NN + k0 + lk);
        const float4 vv = *(const float4*)(V0 + (size_t)(rb + lr) * NN + k0 + lk);
        const float4 gv = *(const float4*)(G + (size_t)(k0 + lr) * NN + cb + lk);
        __syncthreads();
        Ht[lk + 0][lr] = (kk * fmaf(a, vv.x, mv.x) > 0.f) ? 1.f : 0.f;
        Ht[lk + 1][lr] = (kk * fmaf(a, vv.y, mv.y) > 0.f) ? 1.f : 0.f;
        Ht[lk + 2][lr] = (kk * fmaf(a, vv.z, mv.z) > 0.f) ? 1.f : 0.f;
        Ht[lk + 3][lr] = (kk * fmaf(a, vv.w, mv.w) > 0.f) ? 1.f : 0.f;
        Bt[lr][lk + 0] = gv.x; Bt[lr][lk + 1] = gv.y;
        Bt[lr][lk + 2] = gv.z; Bt[lr][lk + 3] = gv.w;
        __syncthreads();

#pragma unroll
        for (int k = 0; k < 32; ++k) {
            const float2 av = *(const float2*)&Ht[k][2 * ty];
            const float2 bv = *(const float2*)&Bt[k][2 * tx];
            acc[0][0] = fmaf(av.x, bv.x, acc[0][0]);
            acc[0][1] = fmaf(av.x, bv.y, acc[0][1]);
            acc[1][0] = fmaf(av.y, bv.x, acc[1][0]);
            acc[1][1] = fmaf(av.y, bv.y, acc[1][1]);
        }
    }

#pragma unroll
    for (int i = 0; i < 2; ++i) {
        *(float2*)(ACC0 + (size_t)(rb + 2 * ty + i) * NN + cb + 2 * tx) =
            make_float2(acc[i][0], acc[i][1]);
    }

    if (rb == 0) {
        __syncthreads();
        float* red = (float*)Ht;
        const int c = cb + (tid & 31);
        const int g = tid >> 5;
        float s = 0.f;
#pragma unroll 8
        for (int bp = 64 * g; bp < 64 * g + 64; ++bp)
            s += G[(size_t)bp * NN + c];
        red[g * 32 + (tid & 31)] = s;
        __syncthreads();
        if (g == 0) {
            const int cc = tid & 31;
            const float tot =
                ((red[cc] + red[32 + cc]) + (red[64 + cc] + red[96 + cc])) +
                ((red[128 + cc] + red[160 + cc]) + (red[192 + cc] + red[224 + cc]));
            gs[c] = tot;
        }
    }
}

// ---- Main recurrence (round-13 snn_bits7 verbatim): 512 blocks x 512 thr.
// t=0: acc := ACC0. t>=1: frozen = 1 barrier; transient = list build +
// named-scalar 8-wide apply with 8 independent partial accumulators.
__global__ __launch_bounds__(512, 4) void snn_bits7_kernel(
    const float* __restrict__ M, const float* __restrict__ G,
    const float* __restrict__ V0, const float* __restrict__ ACC0,
    const float* __restrict__ gs, const float* __restrict__ alpha,
    const float* __restrict__ eta, const float* __restrict__ beta,
    unsigned* __restrict__ sp, int T)
{
    const int tid = threadIdx.x;
    const int w = tid >> 6;
    const int lane = tid & 63;
    const int r = blockIdx.x;

    __shared__ unsigned long long lflag[2];
    __shared__ int wcnt[8];
    __shared__ unsigned short list[528] __attribute__((aligned(16)));

    const float a = alpha[0], e = eta[0], bt = beta[0];
    const float kk = 0.2f;
    const float dd = 0.36787944117144233f;   // exp(-1)
    const float Vth = 0.2f;

    const size_t rc = (size_t)r * NN + tid;
    const float m = M[rc];
    float v = V0[rc];
    const float cg = e * bt * gs[tid];
    const float* Gc = G + tid;

    float acc;
    float em;
    unsigned long long oldw;

    // ---- t = 0: bulk apply comes from ACC0
    {
        const float u = kk * fmaf(a, v, m * 1.0f);
        const unsigned long long hb = __ballot(u > 0.f);
        const unsigned long long sb = __ballot(u > Vth);
        if (lane == 0)
            *(unsigned long long*)(sp + (size_t)r * 16 + 2 * w) = sb;
        oldw = hb;
        acc = ACC0[rc];
        v = fmaf(dd, v, fmaf(e, acc, cg));
        em = dd;
    }

    for (int t = 1; t < T; ++t) {
        const float u = kk * fmaf(a, v, m * em);
        const unsigned long long hb = __ballot(u > 0.f);
        const unsigned long long sb = __ballot(u > Vth);
        const unsigned long long xw = hb ^ oldw;
        const int p = t & 1;
        if (lane == 0) {
            ((unsigned char*)&lflag[p])[w] = (xw != 0ull) ? (unsigned char)1 : (unsigned char)0;
            wcnt[w] = (int)__popcll(xw);
            *(unsigned long long*)(sp + ((size_t)t * NN + r) * 16 + 2 * w) = sb;
        }
        __syncthreads();   // B1

        if (lflag[p] != 0ull) {
            const int c0 = wcnt[0], c1 = wcnt[1], c2 = wcnt[2], c3 = wcnt[3];
            const int c4 = wcnt[4], c5 = wcnt[5], c6 = wcnt[6], c7 = wcnt[7];
            const int ntot = ((c0 + c1) + (c2 + c3)) + ((c4 + c5) + (c6 + c7));
            int base = 0;
            if (w > 0) base += c0;
            if (w > 1) base += c1;
            if (w > 2) base += c2;
            if (w > 3) base += c3;
            if (w > 4) base += c4;
            if (w > 5) base += c5;
            if (w > 6) base += c6;

            if ((xw >> lane) & 1ull) {
                const int pos = (int)__popcll(xw & ((1ull << lane) - 1ull));
                const unsigned row = (unsigned)((w << 6) + lane);
                const unsigned sgn = (unsigned)((hb >> lane) & 1ull) << 15;
                list[base + pos] = (unsigned short)(row | sgn);
            }
            __syncthreads();   // B2: list ready

            float s0 = 0.f, s1 = 0.f, s2 = 0.f, s3 = 0.f;
            float s4 = 0.f, s5 = 0.f, s6 = 0.f, s7 = 0.f;
            for (int j = 0; j < ntot; j += 8) {
                const uint4 le = *(const uint4*)(list + j);
                const unsigned e0 = le.x & 0xFFFFu, e1 = le.x >> 16;
                const unsigned e2 = le.y & 0xFFFFu, e3 = le.y >> 16;
                const unsigned e4 = le.z & 0xFFFFu, e5 = le.z >> 16;
                const unsigned e6 = le.w & 0xFFFFu, e7 = le.w >> 16;
                const float g0 = Gc[(size_t)(e0 & 511u) << 9];
                const float g1 = Gc[(size_t)(e1 & 511u) << 9];
                const float g2 = Gc[(size_t)(e2 & 511u) << 9];
                const float g3 = Gc[(size_t)(e3 & 511u) << 9];
                const float g4 = Gc[(size_t)(e4 & 511u) << 9];
                const float g5 = Gc[(size_t)(e5 & 511u) << 9];
                const float g6 = Gc[(size_t)(e6 & 511u) << 9];
                const float g7 = Gc[(size_t)(e7 & 511u) << 9];
                s0 += (j + 0 < ntot) ? ((e0 & 0x8000u) ? g0 : -g0) : 0.0f;
                s1 += (j + 1 < ntot) ? ((e1 & 0x8000u) ? g1 : -g1) : 0.0f;
                s2 += (j + 2 < ntot) ? ((e2 & 0x8000u) ? g2 : -g2) : 0.0f;
                s3 += (j + 3 < ntot) ? ((e3 & 0x8000u) ? g3 : -g3) : 0.0f;
                s4 += (j + 4 < ntot) ? ((e4 & 0x8000u) ? g4 : -g4) : 0.0f;
                s5 += (j + 5 < ntot) ? ((e5 & 0x8000u) ? g5 : -g5) : 0.0f;
                s6 += (j + 6 < ntot) ? ((e6 & 0x8000u) ? g6 : -g6) : 0.0f;
                s7 += (j + 7 < ntot) ? ((e7 & 0x8000u) ? g7 : -g7) : 0.0f;
            }
            acc += ((s0 + s1) + (s2 + s3)) + ((s4 + s5) + (s6 + s7));
        }

        oldw = hb;
        v = fmaf(dd, v, fmaf(e, acc, cg));
        em *= dd;
    }
}

// ---- Expand: out[t][b][o] = bit b of sp[t][o]. Coalesced float4 stores.
__global__ __launch_bounds__(256) void expand_kernel(
    const unsigned* __restrict__ sp, float* __restrict__ out)
{
    const int tid = threadIdx.x;
    const int t = blockIdx.x >> 3;
    const int bt8 = blockIdx.x & 7;

    __shared__ uint2 sh[NN];
    const uint2* spw = (const uint2*)sp;
    sh[tid]       = spw[((size_t)t * NN + tid) * 8 + bt8];
    sh[tid + 256] = spw[((size_t)t * NN + tid + 256) * 8 + bt8];
    __syncthreads();

    const int b = bt8 * 64 + (tid >> 2);
    const int sub = tid & 3;
    const int rw = (tid >> 2) >> 5;
    const int bit = b & 31;
    float* op = out + (size_t)t * (NN * NN) + (size_t)b * NN;

#pragma unroll 4
    for (int i = 0; i < 32; ++i) {
        const int o = sub * 4 + i * 16;
        const uint2 w0 = sh[o];
        const uint2 w1 = sh[o + 1];
        const uint2 w2 = sh[o + 2];
        const uint2 w3 = sh[o + 3];
        float4 f;
        f.x = (float)(((rw ? w0.y : w0.x) >> bit) & 1u);
        f.y = (float)(((rw ? w1.y : w1.x) >> bit) & 1u);
        f.z = (float)(((rw ? w2.y : w2.x) >> bit) & 1u);
        f.w = (float)(((rw ? w3.y : w3.x) >> bit) & 1u);
        *(float4*)(op + o) = f;
    }
}

// ================= Fallback path (tiny ws) =================
__global__ __launch_bounds__(256) void gemm64_kernel(
    const float* __restrict__ x, const float* __restrict__ W,
    const float* __restrict__ P0, const float* __restrict__ bias,
    float* __restrict__ M, float* __restrict__ V0, float* __restrict__ G)
{
    const int tid = threadIdx.x;
    const int bid = blockIdx.x;
    const int out = bid >> 6;
    const int tl = bid & 63;
    const int rb = (tl >> 3) << 6;
    const int cb = (tl & 7) << 6;

    const float* A = ((out == 0) ? W : (out == 1) ? P0 : x) + (size_t)rb * NN;
    const float* Bx = x + (size_t)cb * NN;
    float* D = (out == 0) ? M : (out == 1) ? V0 : G;

    const int tx = tid & 15;
    const int ty = tid >> 4;

    __shared__ float At[32][68];
    __shared__ float Bt[32][68];

    const int lr = tid >> 2;
    const int lk = (tid & 3) << 3;

    float acc[4][4] = {{0.f,0.f,0.f,0.f},{0.f,0.f,0.f,0.f},
                       {0.f,0.f,0.f,0.f},{0.f,0.f,0.f,0.f}};

    float4 a0 = *(const float4*)(A + (size_t)lr * NN + lk);
    float4 a1 = *(const float4*)(A + (size_t)lr * NN + lk + 4);
    float4 b0 = *(const float4*)(Bx + (size_t)lr * NN + lk);
    float4 b1 = *(const float4*)(Bx + (size_t)lr * NN + lk + 4);

    for (int c = 0; c < 16; ++c) {
        __syncthreads();
        At[lk + 0][lr] = a0.x; At[lk + 1][lr] = a0.y;
        At[lk + 2][lr] = a0.z; At[lk + 3][lr] = a0.w;
        At[lk + 4][lr] = a1.x; At[lk + 5][lr] = a1.y;
        At[lk + 6][lr] = a1.z; At[lk + 7][lr] = a1.w;
        Bt[lk + 0][lr] = b0.x; Bt[lk + 1][lr] = b0.y;
        Bt[lk + 2][lr] = b0.z; Bt[lk + 3][lr] = b0.w;
        Bt[lk + 4][lr] = b1.x; Bt[lk + 5][lr] = b1.y;
        Bt[lk + 6][lr] = b1.z; Bt[lk + 7][lr] = b1.w;
        __syncthreads();

        if (c < 15) {
            const int k0 = (c + 1) << 5;
            a0 = *(const float4*)(A + (size_t)lr * NN + k0 + lk);
            a1 = *(const float4*)(A + (size_t)lr * NN + k0 + lk + 4);
            b0 = *(const float4*)(Bx + (size_t)lr * NN + k0 + lk);
            b1 = *(const float4*)(Bx + (size_t)lr * NN + k0 + lk + 4);
        }

#pragma unroll
        for (int k = 0; k < 32; ++k) {
            const float4 av = *(const float4*)&At[k][4 * ty];
            const float4 bv = *(const float4*)&Bt[k][4 * tx];
            const float avs[4] = {av.x, av.y, av.z, av.w};
            const float bvs[4] = {bv.x, bv.y, bv.z, bv.w};
#pragma unroll
            for (int i = 0; i < 4; ++i)
#pragma unroll
                for (int j = 0; j < 4; ++j)
                    acc[i][j] = fmaf(avs[i], bvs[j], acc[i][j]);
        }
    }

#pragma unroll
    for (int i = 0; i < 4; ++i) {
        const int r = rb + 4 * ty + i;
        float4 o = make_float4(acc[i][0], acc[i][1], acc[i][2], acc[i][3]);
        if (out == 0) {
            const float bb = bias[r];
            o.x = fmaxf(o.x + bb, 0.f); o.y = fmaxf(o.y + bb, 0.f);
            o.z = fmaxf(o.z + bb, 0.f); o.w = fmaxf(o.w + bb, 0.f);
        }
        *(float4*)(D + (size_t)r * NN + cb + 4 * tx) = o;
    }
}

__global__ __launch_bounds__(256) void colsum_kernel(
    const float* __restrict__ G, float* __restrict__ gs)
{
    __shared__ float red[4][64];
    const int tid = threadIdx.x;
    const int c = (blockIdx.x << 6) + (tid & 63);
    const int g = tid >> 6;
    float s = 0.f;
#pragma unroll 8
    for (int bp = 128 * g; bp < 128 * g + 128; ++bp) s += G[(size_t)bp * NN + c];
    if (g > 0) red[g][tid & 63] = s;
    __syncthreads();
    if (g == 0) gs[c] = ((s + red[1][tid & 63]) + red[2][tid & 63]) + red[3][tid & 63];
}

__global__ __launch_bounds__(256) void snn_step_kernel(
    const float* __restrict__ M, const float* __restrict__ G,
    const float* __restrict__ V0, const float* __restrict__ gs,
    const float* __restrict__ alpha, const float* __restrict__ eta,
    const float* __restrict__ beta, float* __restrict__ out, int T)
{
    const int j = threadIdx.x;
    const int r0 = blockIdx.x * 2;
    const int c0 = 2 * j;
    const float a = alpha[0], e = eta[0], bt = beta[0];
    const float kk = 0.2f, dd = 0.36787944117144233f, Vth = 0.2f;

    float v00 = V0[r0 * NN + c0];
    float v01 = V0[r0 * NN + c0 + 1];
    float v10 = V0[(r0 + 1) * NN + c0];
    float v11 = V0[(r0 + 1) * NN + c0 + 1];
    const float m00 = M[r0 * NN + c0];
    const float m01 = M[r0 * NN + c0 + 1];
    const float m10 = M[(r0 + 1) * NN + c0];
    const float m11 = M[(r0 + 1) * NN + c0 + 1];
    const float gs0 = gs[c0];
    const float gs1 = gs[c0 + 1];

    __shared__ float2 hp[NN];
    float em = 1.0f;
    const float2* Gcol = (const float2*)G + j;

    for (int t = 0; t < T; ++t) {
        const float u00 = kk * (m00 * em + a * v00);
        const float u01 = kk * (m01 * em + a * v01);
        const float u10 = kk * (m10 * em + a * v10);
        const float u11 = kk * (m11 * em + a * v11);

        float* outp = out + (size_t)t * (NN * NN);
        float2 sA = make_float2(u00 > Vth ? 1.f : 0.f, u10 > Vth ? 1.f : 0.f);
        float2 sB = make_float2(u01 > Vth ? 1.f : 0.f, u11 > Vth ? 1.f : 0.f);
        *(float2*)(outp + (size_t)c0 * NN + r0) = sA;
        *(float2*)(outp + (size_t)(c0 + 1) * NN + r0) = sB;

        hp[c0]     = make_float2(u00 > 0.f ? 1.f : 0.f, u10 > 0.f ? 1.f : 0.f);
        hp[c0 + 1] = make_float2(u01 > 0.f ? 1.f : 0.f, u11 > 0.f ? 1.f : 0.f);
        __syncthreads();

        float acc00 = 0.f, acc01 = 0.f, acc10 = 0.f, acc11 = 0.f;
#pragma unroll 8
        for (int bp = 0; bp < NN; ++bp) {
            float2 h = hp[bp];
            float2 g = Gcol[(size_t)bp * 256];
            acc00 = fmaf(h.x, g.x, acc00);
            acc01 = fmaf(h.x, g.y, acc01);
            acc10 = fmaf(h.y, g.x, acc10);
            acc11 = fmaf(h.y, g.y, acc11);
        }

        v00 = dd * v00 + e * (acc00 + bt * gs0);
        v01 = dd * v01 + e * (acc01 + bt * gs1);
        v10 = dd * v10 + e * (acc10 + bt * gs0);
        v11 = dd * v11 + e * (acc11 + bt * gs1);
        em *= dd;
        __syncthreads();
    }
}

extern "C" void kernel_launch(void* const* d_in, const int* in_sizes, int n_in,
                              void* d_out, int out_size, void* d_ws, size_t ws_size,
                              hipStream_t stream)
{
    const float* x     = (const float*)d_in[0];
    const float* W     = (const float*)d_in[1];
    const float* bias  = (const float*)d_in[2];
    const float* alpha = (const float*)d_in[3];
    const float* eta   = (const float*)d_in[4];
    const float* beta  = (const float*)d_in[5];
    const float* P0    = (const float*)d_in[6];
    (void)in_sizes; (void)n_in;

    const int T = out_size / (NN * NN);

    float* ws   = (float*)d_ws;
    float* part = ws;                          // 12 x [512,512] split partials
    float* M    = ws + 12 * NN * NN;           // finals
    float* V0   = ws + 13 * NN * NN;
    float* G    = ws + 14 * NN * NN;
    float* ACC0 = ws + 15 * NN * NN;
    float* gsv  = ws + 16 * NN * NN;           // [512]
    unsigned* sp = (unsigned*)(gsv + NN);      // [T][512][16] words

    const size_t need_main = ((size_t)16 * NN * NN + NN) * 4 + (size_t)T * NN * 16 * 4;

    if (ws_size >= need_main) {
        hipLaunchKernelGGL(gemm_splitk_kernel, dim3(768), dim3(256), 0, stream,
                           x, W, P0, part);
        hipLaunchKernelGGL(combine_kernel, dim3(768), dim3(256), 0, stream,
                           part, bias, M, V0, G);
        hipLaunchKernelGGL(acc0cs_kernel, dim3(256), dim3(256), 0, stream,
                           M, V0, G, alpha, ACC0, gsv);
        hipLaunchKernelGGL(snn_bits7_kernel, dim3(NN), dim3(512), 0, stream,
                           M, G, V0, ACC0, gsv, alpha, eta, beta, sp, T);
        hipLaunchKernelGGL(expand_kernel, dim3(T * 8), dim3(256), 0, stream,
                           sp, (float*)d_out);
    } else {
        float* Mf  = ws;
        float* V0f = ws + NN * NN;
        float* Gf  = ws + 2 * NN * NN;
        float* gs2 = ws + 3 * NN * NN;
        hipLaunchKernelGGL(gemm64_kernel, dim3(192), dim3(256), 0, stream,
                           x, W, P0, bias, Mf, V0f, Gf);
        hipLaunchKernelGGL(colsum_kernel, dim3(8), dim3(256), 0, stream, Gf, gs2);
        hipLaunchKernelGGL(snn_step_kernel, dim3(256), dim3(256), 0, stream,
                           Mf, Gf, V0f, gs2, alpha, eta, beta, (float*)d_out, T);
    }
}

// Round 16
// 109.629 us; speedup vs baseline: 1.4769x; 1.0617x over previous
//
#include <hip/hip_runtime.h>

// B = IN = OUT = 512; T from out_size.
// v_t = P_t @ x^T [OUT,B]; G = x@x^T [B,B]
//   u = k*(M*e^{-t} + a*v);  h = (u>0);  s = (u>0.2)
//   v' = d*v + e*(h@G + bt*colsum(G))
// Round-16:
//  acc0_splitk: H0@G as split-K x8 64x64/4x4 GEMM (grid 512, 2 blocks/CU) --
//    round-15's acc0cs was the round-4 latency-bound shape (1 block/CU, 2x2,
//    full-K). gs colsum partials fused into tile-row-0 blocks. Partials alias
//    the dead split-K `part` buffer.
//  snn_bits9: certified barrier-free tail. On a zero-flip step, check per
//    thread: u(t+k) = uInf + dd^k*(u-uInf); if |uInf| > dd*|C| + 1e-4*(...)
//    and sign(uInf)==sign(u) for ALL threads (ballot + 1 barrier), h can
//    never flip again -> remaining steps run with no barriers/LDS, same fma
//    sequence (bit-identical v and s).

#define NN 512

// ---- Split-K GEMM: grid 768 = 3 outputs x 4 K-quarters x 64 tiles(64x64).
__global__ __launch_bounds__(256) void gemm_splitk_kernel(
    const float* __restrict__ x, const float* __restrict__ W,
    const float* __restrict__ P0, float* __restrict__ part)
{
    const int tid = threadIdx.x;
    const int bid = blockIdx.x;          // 0..767
    const int out = bid >> 8;            // 0..2
    const int rem = bid & 255;
    const int kq = rem >> 6;             // 0..3
    const int tl = rem & 63;
    const int rb = (tl >> 3) << 6;
    const int cb = (tl & 7) << 6;
    const int kbase = kq << 7;           // 0,128,256,384

    const float* A = ((out == 0) ? W : (out == 1) ? P0 : x) + (size_t)rb * NN;
    const float* Bx = x + (size_t)cb * NN;
    float* D = part + (size_t)(out * 4 + kq) * NN * NN;

    const int tx = tid & 15;
    const int ty = tid >> 4;

    __shared__ float At[32][68];
    __shared__ float Bt[32][68];

    const int lr = tid >> 2;
    const int lk = (tid & 3) << 3;

    float acc[4][4] = {{0.f,0.f,0.f,0.f},{0.f,0.f,0.f,0.f},
                       {0.f,0.f,0.f,0.f},{0.f,0.f,0.f,0.f}};

    float4 a0 = *(const float4*)(A + (size_t)lr * NN + kbase + lk);
    float4 a1 = *(const float4*)(A + (size_t)lr * NN + kbase + lk + 4);
    float4 b0 = *(const float4*)(Bx + (size_t)lr * NN + kbase + lk);
    float4 b1 = *(const float4*)(Bx + (size_t)lr * NN + kbase + lk + 4);

    for (int c = 0; c < 4; ++c) {
        __syncthreads();
        At[lk + 0][lr] = a0.x; At[lk + 1][lr] = a0.y;
        At[lk + 2][lr] = a0.z; At[lk + 3][lr] = a0.w;
        At[lk + 4][lr] = a1.x; At[lk + 5][lr] = a1.y;
        At[lk + 6][lr] = a1.z; At[lk + 7][lr] = a1.w;
        Bt[lk + 0][lr] = b0.x; Bt[lk + 1][lr] = b0.y;
        Bt[lk + 2][lr] = b0.z; Bt[lk + 3][lr] = b0.w;
        Bt[lk + 4][lr] = b1.x; Bt[lk + 5][lr] = b1.y;
        Bt[lk + 6][lr] = b1.z; Bt[lk + 7][lr] = b1.w;
        __syncthreads();

        if (c < 3) {
            const int k0 = kbase + ((c + 1) << 5);
            a0 = *(const float4*)(A + (size_t)lr * NN + k0 + lk);
            a1 = *(const float4*)(A + (size_t)lr * NN + k0 + lk + 4);
            b0 = *(const float4*)(Bx + (size_t)lr * NN + k0 + lk);
            b1 = *(const float4*)(Bx + (size_t)lr * NN + k0 + lk + 4);
        }

#pragma unroll
        for (int k = 0; k < 32; ++k) {
            const float4 av = *(const float4*)&At[k][4 * ty];
            const float4 bv = *(const float4*)&Bt[k][4 * tx];
            const float avs[4] = {av.x, av.y, av.z, av.w};
            const float bvs[4] = {bv.x, bv.y, bv.z, bv.w};
#pragma unroll
            for (int i = 0; i < 4; ++i)
#pragma unroll
                for (int j = 0; j < 4; ++j)
                    acc[i][j] = fmaf(avs[i], bvs[j], acc[i][j]);
        }
    }

#pragma unroll
    for (int i = 0; i < 4; ++i) {
        const int r = rb + 4 * ty + i;
        *(float4*)(D + (size_t)r * NN + cb + 4 * tx) =
            make_float4(acc[i][0], acc[i][1], acc[i][2], acc[i][3]);
    }
}

// ---- combine: finals from partials, pairwise sum; bias+relu for M.
__global__ __launch_bounds__(256) void combine_kernel(
    const float* __restrict__ part, const float* __restrict__ bias,
    float* __restrict__ M, float* __restrict__ V0, float* __restrict__ G)
{
    const int idx = blockIdx.x * 256 + threadIdx.x;   // 0..196607
    const int out = idx >> 16;                        // 0..2
    const int io = idx & 65535;
    const float4* p = (const float4*)(part + (size_t)out * 4 * NN * NN);
    const float4 p0 = p[io];
    const float4 p1 = p[io + 65536];
    const float4 p2 = p[io + 131072];
    const float4 p3 = p[io + 196608];
    float4 s;
    s.x = (p0.x + p1.x) + (p2.x + p3.x);
    s.y = (p0.y + p1.y) + (p2.y + p3.y);
    s.z = (p0.z + p1.z) + (p2.z + p3.z);
    s.w = (p0.w + p1.w) + (p2.w + p3.w);
    if (out == 0) {
        const float bb = bias[io >> 7];
        s.x = fmaxf(s.x + bb, 0.f); s.y = fmaxf(s.y + bb, 0.f);
        s.z = fmaxf(s.z + bb, 0.f); s.w = fmaxf(s.w + bb, 0.f);
        ((float4*)M)[io] = s;
    } else if (out == 1) {
        ((float4*)V0)[io] = s;
    } else {
        ((float4*)G)[io] = s;
    }
}

// ---- acc0 split-K x8: ACC0p[kq] = H0[:,kq-slice] @ G[kq-slice,:],
// H0 = (kk*fmaf(a,V0,M) > 0). grid 512 = 8 kq x 64 tiles(64x64), 4x4 micro.
// Tile-row-0 blocks also emit gs partial colsums for their kq slice.
__global__ __launch_bounds__(256) void acc0_splitk_kernel(
    const float* __restrict__ M, const float* __restrict__ V0,
    const float* __restrict__ G, const float* __restrict__ alpha,
    float* __restrict__ ACC0p, float* __restrict__ gsp)
{
    const int tid = threadIdx.x;
    const int bid = blockIdx.x;          // 0..511
    const int kq = bid >> 6;             // 0..7
    const int tl = bid & 63;
    const int rb = (tl >> 3) << 6;
    const int cb = (tl & 7) << 6;
    const int kbase = kq << 6;           // 64-wide K slice

    const float a = alpha[0];
    const float kk = 0.2f;

    const int tx = tid & 15;
    const int ty = tid >> 4;

    __shared__ float At[32][68];
    __shared__ float Bt[32][68];

    const int ar = tid >> 2;             // 0..63 (A row)
    const int akk = (tid & 3) << 3;      // 0,8,16,24
    const int kb = tid >> 3;             // 0..31 (B k-row)
    const int cl = (tid & 7) << 3;       // 0,8,...,56

    float acc[4][4] = {{0.f,0.f,0.f,0.f},{0.f,0.f,0.f,0.f},
                       {0.f,0.f,0.f,0.f},{0.f,0.f,0.f,0.f}};

    float4 m0 = *(const float4*)(M + (size_t)(rb + ar) * NN + kbase + akk);
    float4 m1 = *(const float4*)(M + (size_t)(rb + ar) * NN + kbase + akk + 4);
    float4 v0 = *(const float4*)(V0 + (size_t)(rb + ar) * NN + kbase + akk);
    float4 v1 = *(const float4*)(V0 + (size_t)(rb + ar) * NN + kbase + akk + 4);
    float4 g0 = *(const float4*)(G + (size_t)(kbase + kb) * NN + cb + cl);
    float4 g1 = *(const float4*)(G + (size_t)(kbase + kb) * NN + cb + cl + 4);

    for (int c = 0; c < 2; ++c) {
        __syncthreads();
        At[akk + 0][ar] = (kk * fmaf(a, v0.x, m0.x) > 0.f) ? 1.f : 0.f;
        At[akk + 1][ar] = (kk * fmaf(a, v0.y, m0.y) > 0.f) ? 1.f : 0.f;
        At[akk + 2][ar] = (kk * fmaf(a, v0.z, m0.z) > 0.f) ? 1.f : 0.f;
        At[akk + 3][ar] = (kk * fmaf(a, v0.w, m0.w) > 0.f) ? 1.f : 0.f;
        At[akk + 4][ar] = (kk * fmaf(a, v1.x, m1.x) > 0.f) ? 1.f : 0.f;
        At[akk + 5][ar] = (kk * fmaf(a, v1.y, m1.y) > 0.f) ? 1.f : 0.f;
        At[akk + 6][ar] = (kk * fmaf(a, v1.z, m1.z) > 0.f) ? 1.f : 0.f;
        At[akk + 7][ar] = (kk * fmaf(a, v1.w, m1.w) > 0.f) ? 1.f : 0.f;
        Bt[kb][cl + 0] = g0.x; Bt[kb][cl + 1] = g0.y;
        Bt[kb][cl + 2] = g0.z; Bt[kb][cl + 3] = g0.w;
        Bt[kb][cl + 4] = g1.x; Bt[kb][cl + 5] = g1.y;
        Bt[kb][cl + 6] = g1.z; Bt[kb][cl + 7] = g1.w;
        __syncthreads();

        if (c < 1) {
            const int k0 = kbase + 32;
            m0 = *(const float4*)(M + (size_t)(rb + ar) * NN + k0 + akk);
            m1 = *(const float4*)(M + (size_t)(rb + ar) * NN + k0 + akk + 4);
            v0 = *(const float4*)(V0 + (size_t)(rb + ar) * NN + k0 + akk);
            v1 = *(const float4*)(V0 + (size_t)(rb + ar) * NN + k0 + akk + 4);
            g0 = *(const float4*)(G + (size_t)(k0 + kb) * NN + cb + cl);
            g1 = *(const float4*)(G + (size_t)(k0 + kb) * NN + cb + cl + 4);
        }

#pragma unroll
        for (int k = 0; k < 32; ++k) {
            const float4 av = *(const float4*)&At[k][4 * ty];
            const float4 bv = *(const float4*)&Bt[k][4 * tx];
            const float avs[4] = {av.x, av.y, av.z, av.w};
            const float bvs[4] = {bv.x, bv.y, bv.z, bv.w};
#pragma unroll
            for (int i = 0; i < 4; ++i)
#pragma unroll
                for (int j = 0; j < 4; ++j)
                    acc[i][j] = fmaf(avs[i], bvs[j], acc[i][j]);
        }
    }

    float* Dp = ACC0p + (size_t)kq * NN * NN;
#pragma unroll
    for (int i = 0; i < 4; ++i) {
        *(float4*)(Dp + (size_t)(rb + 4 * ty + i) * NN + cb + 4 * tx) =
            make_float4(acc[i][0], acc[i][1], acc[i][2], acc[i][3]);
    }

    // fused gs partials: tile-row-0 blocks sum their 64-row kq slice
    if ((tl >> 3) == 0) {
        __syncthreads();
        float* red = &At[0][0];
        const int c = cb + (tid & 63);
        const int g = tid >> 6;           // 0..3: rows kbase+16g..+15
        float s = 0.f;
#pragma unroll 16
        for (int i = 0; i < 16; ++i)
            s += G[(size_t)(kbase + 16 * g + i) * NN + c];
        red[g * 64 + (tid & 63)] = s;
        __syncthreads();
        if (g == 0) {
            const int cc = tid & 63;
            gsp[kq * NN + c] =
                (red[cc] + red[64 + cc]) + (red[128 + cc] + red[192 + cc]);
        }
    }
}

// ---- Main recurrence: 512 blocks x 512 threads. Thread owns col c = tid.
// t=0: acc := sum of 8 ACC0 partials. t>=1: frozen = 1 barrier; transient =
// list build + 8-wide named-scalar apply. Zero-flip steps attempt the
// certificate; once certified, the tail runs barrier-free (bit-identical fma).
__global__ __launch_bounds__(512, 4) void snn_bits9_kernel(
    const float* __restrict__ M, const float* __restrict__ G,
    const float* __restrict__ V0, const float* __restrict__ ACC0p,
    const float* __restrict__ gsp, const float* __restrict__ alpha,
    const float* __restrict__ eta, const float* __restrict__ beta,
    unsigned* __restrict__ sp, int T)
{
    const int tid = threadIdx.x;
    const int w = tid >> 6;
    const int lane = tid & 63;
    const int r = blockIdx.x;

    __shared__ unsigned long long lflag[2];
    __shared__ unsigned long long certf[2];
    __shared__ int wcnt[8];
    __shared__ unsigned short list[528] __attribute__((aligned(16)));

    const float a = alpha[0], e = eta[0], bt = beta[0];
    const float kk = 0.2f;
    const float dd = 0.36787944117144233f;   // exp(-1)
    const float Vth = 0.2f;

    const size_t rc = (size_t)r * NN + tid;
    const float m = M[rc];
    float v = V0[rc];
    const float gsum =
        ((gsp[tid] + gsp[NN + tid]) + (gsp[2 * NN + tid] + gsp[3 * NN + tid])) +
        ((gsp[4 * NN + tid] + gsp[5 * NN + tid]) + (gsp[6 * NN + tid] + gsp[7 * NN + tid]));
    const float cg = e * bt * gsum;
    const float* Gc = G + tid;

    float acc;
    float em;
    unsigned long long oldw;

    // ---- t = 0: bulk apply from the 8 ACC0 partials
    {
        const float u = kk * fmaf(a, v, m * 1.0f);
        const unsigned long long hb = __ballot(u > 0.f);
        const unsigned long long sb = __ballot(u > Vth);
        if (lane == 0)
            *(unsigned long long*)(sp + (size_t)r * 16 + 2 * w) = sb;
        oldw = hb;
        const float* A0 = ACC0p + rc;
        const size_t S = (size_t)NN * NN;
        acc = ((A0[0] + A0[S]) + (A0[2 * S] + A0[3 * S]))
            + ((A0[4 * S] + A0[5 * S]) + (A0[6 * S] + A0[7 * S]));
        v = fmaf(dd, v, fmaf(e, acc, cg));
        em = dd;
    }

    for (int t = 1; t < T; ++t) {
        const float u = kk * fmaf(a, v, m * em);
        const unsigned long long hb = __ballot(u > 0.f);
        const unsigned long long sb = __ballot(u > Vth);
        const unsigned long long xw = hb ^ oldw;
        const int p = t & 1;
        if (lane == 0) {
            ((unsigned char*)&lflag[p])[w] = (xw != 0ull) ? (unsigned char)1 : (unsigned char)0;
            wcnt[w] = (int)__popcll(xw);
            *(unsigned long long*)(sp + ((size_t)t * NN + r) * 16 + 2 * w) = sb;
        }
        __syncthreads();   // B1

        bool certified = false;
        if (lflag[p] != 0ull) {
            const int c0 = wcnt[0], c1 = wcnt[1], c2 = wcnt[2], c3 = wcnt[3];
            const int c4 = wcnt[4], c5 = wcnt[5], c6 = wcnt[6], c7 = wcnt[7];
            const int ntot = ((c0 + c1) + (c2 + c3)) + ((c4 + c5) + (c6 + c7));
            int base = 0;
            if (w > 0) base += c0;
            if (w > 1) base += c1;
            if (w > 2) base += c2;
            if (w > 3) base += c3;
            if (w > 4) base += c4;
            if (w > 5) base += c5;
            if (w > 6) base += c6;

            if ((xw >> lane) & 1ull) {
                const int pos = (int)__popcll(xw & ((1ull << lane) - 1ull));
                const unsigned row = (unsigned)((w << 6) + lane);
                const unsigned sgn = (unsigned)((hb >> lane) & 1ull) << 15;
                list[base + pos] = (unsigned short)(row | sgn);
            }
            __syncthreads();   // B2: list ready

            float s0 = 0.f, s1 = 0.f, s2 = 0.f, s3 = 0.f;
            float s4 = 0.f, s5 = 0.f, s6 = 0.f, s7 = 0.f;
            for (int j = 0; j < ntot; j += 8) {
                const uint4 le = *(const uint4*)(list + j);
                const unsigned e0 = le.x & 0xFFFFu, e1 = le.x >> 16;
                const unsigned e2 = le.y & 0xFFFFu, e3 = le.y >> 16;
                const unsigned e4 = le.z & 0xFFFFu, e5 = le.z >> 16;
                const unsigned e6 = le.w & 0xFFFFu, e7 = le.w >> 16;
                const float g0 = Gc[(size_t)(e0 & 511u) << 9];
                const float g1 = Gc[(size_t)(e1 & 511u) << 9];
                const float g2 = Gc[(size_t)(e2 & 511u) << 9];
                const float g3 = Gc[(size_t)(e3 & 511u) << 9];
                const float g4 = Gc[(size_t)(e4 & 511u) << 9];
                const float g5 = Gc[(size_t)(e5 & 511u) << 9];
                const float g6 = Gc[(size_t)(e6 & 511u) << 9];
                const float g7 = Gc[(size_t)(e7 & 511u) << 9];
                s0 += (j + 0 < ntot) ? ((e0 & 0x8000u) ? g0 : -g0) : 0.0f;
                s1 += (j + 1 < ntot) ? ((e1 & 0x8000u) ? g1 : -g1) : 0.0f;
                s2 += (j + 2 < ntot) ? ((e2 & 0x8000u) ? g2 : -g2) : 0.0f;
                s3 += (j + 3 < ntot) ? ((e3 & 0x8000u) ? g3 : -g3) : 0.0f;
                s4 += (j + 4 < ntot) ? ((e4 & 0x8000u) ? g4 : -g4) : 0.0f;
                s5 += (j + 5 < ntot) ? ((e5 & 0x8000u) ? g5 : -g5) : 0.0f;
                s6 += (j + 6 < ntot) ? ((e6 & 0x8000u) ? g6 : -g6) : 0.0f;
                s7 += (j + 7 < ntot) ? ((e7 & 0x8000u) ? g7 : -g7) : 0.0f;
            }
            acc += ((s0 + s1) + (s2 + s3)) + ((s4 + s5) + (s6 + s7));
        } else {
            // zero-flip step: attempt certification of the whole tail.
            // u(t+k) = uInf + dd^k*C, C = u - uInf; safe iff |uInf| dominates.
            const float K0 = fmaf(e, acc, cg);
            const float Vinf = K0 / (1.0f - dd);
            const float uInf = kk * (a * Vinf);
            const float C = u - uInf;
            const bool okT = ((uInf > 0.f) == (u > 0.f)) &&
                (fabsf(uInf) > fmaf(dd, fabsf(C),
                                    1e-4f * (fabsf(uInf) + fabsf(C)) + 1e-12f));
            const unsigned long long okm = __ballot(okT);
            if (lane == 0)
                ((unsigned char*)&certf[p])[w] =
                    (okm == 0xFFFFFFFFFFFFFFFFull) ? (unsigned char)1 : (unsigned char)0;
            __syncthreads();   // B2c
            certified = (certf[p] == 0x0101010101010101ull);
        }

        oldw = hb;
        v = fmaf(dd, v, fmaf(e, acc, cg));
        em *= dd;

        if (certified) {
            const float K = fmaf(e, acc, cg);
            for (int t2 = t + 1; t2 < T; ++t2) {
                const float u2 = kk * fmaf(a, v, m * em);
                const unsigned long long sb2 = __ballot(u2 > Vth);
                if (lane == 0)
                    *(unsigned long long*)(sp + ((size_t)t2 * NN + r) * 16 + 2 * w) = sb2;
                v = fmaf(dd, v, K);
                em *= dd;
            }
            return;
        }
    }
}

// ---- Expand: out[t][b][o] = bit b of sp[t][o]. Coalesced float4 stores.
__global__ __launch_bounds__(256) void expand_kernel(
    const unsigned* __restrict__ sp, float* __restrict__ out)
{
    const int tid = threadIdx.x;
    const int t = blockIdx.x >> 3;
    const int bt8 = blockIdx.x & 7;

    __shared__ uint2 sh[NN];
    const uint2* spw = (const uint2*)sp;
    sh[tid]       = spw[((size_t)t * NN + tid) * 8 + bt8];
    sh[tid + 256] = spw[((size_t)t * NN + tid + 256) * 8 + bt8];
    __syncthreads();

    const int b = bt8 * 64 + (tid >> 2);
    const int sub = tid & 3;
    const int rw = (tid >> 2) >> 5;
    const int bit = b & 31;
    float* op = out + (size_t)t * (NN * NN) + (size_t)b * NN;

#pragma unroll 4
    for (int i = 0; i < 32; ++i) {
        const int o = sub * 4 + i * 16;
        const uint2 w0 = sh[o];
        const uint2 w1 = sh[o + 1];
        const uint2 w2 = sh[o + 2];
        const uint2 w3 = sh[o + 3];
        float4 f;
        f.x = (float)(((rw ? w0.y : w0.x) >> bit) & 1u);
        f.y = (float)(((rw ? w1.y : w1.x) >> bit) & 1u);
        f.z = (float)(((rw ? w2.y : w2.x) >> bit) & 1u);
        f.w = (float)(((rw ? w3.y : w3.x) >> bit) & 1u);
        *(float4*)(op + o) = f;
    }
}

// ================= Fallback path (tiny ws) =================
__global__ __launch_bounds__(256) void gemm64_kernel(
    const float* __restrict__ x, const float* __restrict__ W,
    const float* __restrict__ P0, const float* __restrict__ bias,
    float* __restrict__ M, float* __restrict__ V0, float* __restrict__ G)
{
    const int tid = threadIdx.x;
    const int bid = blockIdx.x;
    const int out = bid >> 6;
    const int tl = bid & 63;
    const int rb = (tl >> 3) << 6;
    const int cb = (tl & 7) << 6;

    const float* A = ((out == 0) ? W : (out == 1) ? P0 : x) + (size_t)rb * NN;
    const float* Bx = x + (size_t)cb * NN;
    float* D = (out == 0) ? M : (out == 1) ? V0 : G;

    const int tx = tid & 15;
    const int ty = tid >> 4;

    __shared__ float At[32][68];
    __shared__ float Bt[32][68];

    const int lr = tid >> 2;
    const int lk = (tid & 3) << 3;

    float acc[4][4] = {{0.f,0.f,0.f,0.f},{0.f,0.f,0.f,0.f},
                       {0.f,0.f,0.f,0.f},{0.f,0.f,0.f,0.f}};

    float4 a0 = *(const float4*)(A + (size_t)lr * NN + lk);
    float4 a1 = *(const float4*)(A + (size_t)lr * NN + lk + 4);
    float4 b0 = *(const float4*)(Bx + (size_t)lr * NN + lk);
    float4 b1 = *(const float4*)(Bx + (size_t)lr * NN + lk + 4);

    for (int c = 0; c < 16; ++c) {
        __syncthreads();
        At[lk + 0][lr] = a0.x; At[lk + 1][lr] = a0.y;
        At[lk + 2][lr] = a0.z; At[lk + 3][lr] = a0.w;
        At[lk + 4][lr] = a1.x; At[lk + 5][lr] = a1.y;
        At[lk + 6][lr] = a1.z; At[lk + 7][lr] = a1.w;
        Bt[lk + 0][lr] = b0.x; Bt[lk + 1][lr] = b0.y;
        Bt[lk + 2][lr] = b0.z; Bt[lk + 3][lr] = b0.w;
        Bt[lk + 4][lr] = b1.x; Bt[lk + 5][lr] = b1.y;
        Bt[lk + 6][lr] = b1.z; Bt[lk + 7][lr] = b1.w;
        __syncthreads();

        if (c < 15) {
            const int k0 = (c + 1) << 5;
            a0 = *(const float4*)(A + (size_t)lr * NN + k0 + lk);
            a1 = *(const float4*)(A + (size_t)lr * NN + k0 + lk + 4);
            b0 = *(const float4*)(Bx + (size_t)lr * NN + k0 + lk);
            b1 = *(const float4*)(Bx + (size_t)lr * NN + k0 + lk + 4);
        }

#pragma unroll
        for (int k = 0; k < 32; ++k) {
            const float4 av = *(const float4*)&At[k][4 * ty];
            const float4 bv = *(const float4*)&Bt[k][4 * tx];
            const float avs[4] = {av.x, av.y, av.z, av.w};
            const float bvs[4] = {bv.x, bv.y, bv.z, bv.w};
#pragma unroll
            for (int i = 0; i < 4; ++i)
#pragma unroll
                for (int j = 0; j < 4; ++j)
                    acc[i][j] = fmaf(avs[i], bvs[j], acc[i][j]);
        }
    }

#pragma unroll
    for (int i = 0; i < 4; ++i) {
        const int r = rb + 4 * ty + i;
        float4 o = make_float4(acc[i][0], acc[i][1], acc[i][2], acc[i][3]);
        if (out == 0) {
            const float bb = bias[r];
            o.x = fmaxf(o.x + bb, 0.f); o.y = fmaxf(o.y + bb, 0.f);
            o.z = fmaxf(o.z + bb, 0.f); o.w = fmaxf(o.w + bb, 0.f);
        }
        *(float4*)(D + (size_t)r * NN + cb + 4 * tx) = o;
    }
}

__global__ __launch_bounds__(256) void colsum_kernel(
    const float* __restrict__ G, float* __restrict__ gs)
{
    __shared__ float red[4][64];
    const int tid = threadIdx.x;
    const int c = (blockIdx.x << 6) + (tid & 63);
    const int g = tid >> 6;
    float s = 0.f;
#pragma unroll 8
    for (int bp = 128 * g; bp < 128 * g + 128; ++bp) s += G[(size_t)bp * NN + c];
    if (g > 0) red[g][tid & 63] = s;
    __syncthreads();
    if (g == 0) gs[c] = ((s + red[1][tid & 63]) + red[2][tid & 63]) + red[3][tid & 63];
}

__global__ __launch_bounds__(256) void snn_step_kernel(
    const float* __restrict__ M, const float* __restrict__ G,
    const float* __restrict__ V0, const float* __restrict__ gs,
    const float* __restrict__ alpha, const float* __restrict__ eta,
    const float* __restrict__ beta, float* __restrict__ out, int T)
{
    const int j = threadIdx.x;
    const int r0 = blockIdx.x * 2;
    const int c0 = 2 * j;
    const float a = alpha[0], e = eta[0], bt = beta[0];
    const float kk = 0.2f, dd = 0.36787944117144233f, Vth = 0.2f;

    float v00 = V0[r0 * NN + c0];
    float v01 = V0[r0 * NN + c0 + 1];
    float v10 = V0[(r0 + 1) * NN + c0];
    float v11 = V0[(r0 + 1) * NN + c0 + 1];
    const float m00 = M[r0 * NN + c0];
    const float m01 = M[r0 * NN + c0 + 1];
    const float m10 = M[(r0 + 1) * NN + c0];
    const float m11 = M[(r0 + 1) * NN + c0 + 1];
    const float gs0 = gs[c0];
    const float gs1 = gs[c0 + 1];

    __shared__ float2 hp[NN];
    float em = 1.0f;
    const float2* Gcol = (const float2*)G + j;

    for (int t = 0; t < T; ++t) {
        const float u00 = kk * (m00 * em + a * v00);
        const float u01 = kk * (m01 * em + a * v01);
        const float u10 = kk * (m10 * em + a * v10);
        const float u11 = kk * (m11 * em + a * v11);

        float* outp = out + (size_t)t * (NN * NN);
        float2 sA = make_float2(u00 > Vth ? 1.f : 0.f, u10 > Vth ? 1.f : 0.f);
        float2 sB = make_float2(u01 > Vth ? 1.f : 0.f, u11 > Vth ? 1.f : 0.f);
        *(float2*)(outp + (size_t)c0 * NN + r0) = sA;
        *(float2*)(outp + (size_t)(c0 + 1) * NN + r0) = sB;

        hp[c0]     = make_float2(u00 > 0.f ? 1.f : 0.f, u10 > 0.f ? 1.f : 0.f);
        hp[c0 + 1] = make_float2(u01 > 0.f ? 1.f : 0.f, u11 > 0.f ? 1.f : 0.f);
        __syncthreads();

        float acc00 = 0.f, acc01 = 0.f, acc10 = 0.f, acc11 = 0.f;
#pragma unroll 8
        for (int bp = 0; bp < NN; ++bp) {
            float2 h = hp[bp];
            float2 g = Gcol[(size_t)bp * 256];
            acc00 = fmaf(h.x, g.x, acc00);
            acc01 = fmaf(h.x, g.y, acc01);
            acc10 = fmaf(h.y, g.x, acc10);
            acc11 = fmaf(h.y, g.y, acc11);
        }

        v00 = dd * v00 + e * (acc00 + bt * gs0);
        v01 = dd * v01 + e * (acc01 + bt * gs1);
        v10 = dd * v10 + e * (acc10 + bt * gs0);
        v11 = dd * v11 + e * (acc11 + bt * gs1);
        em *= dd;
        __syncthreads();
    }
}

extern "C" void kernel_launch(void* const* d_in, const int* in_sizes, int n_in,
                              void* d_out, int out_size, void* d_ws, size_t ws_size,
                              hipStream_t stream)
{
    const float* x     = (const float*)d_in[0];
    const float* W     = (const float*)d_in[1];
    const float* bias  = (const float*)d_in[2];
    const float* alpha = (const float*)d_in[3];
    const float* eta   = (const float*)d_in[4];
    const float* beta  = (const float*)d_in[5];
    const float* P0    = (const float*)d_in[6];
    (void)in_sizes; (void)n_in;

    const int T = out_size / (NN * NN);

    float* ws    = (float*)d_ws;
    float* part  = ws;                         // 12 x [512,512] gemm partials
    float* ACC0p = ws;                         // aliases part (dead after combine)
    float* M     = ws + 12 * NN * NN;          // finals
    float* V0    = ws + 13 * NN * NN;
    float* G     = ws + 14 * NN * NN;
    float* gsp   = ws + 15 * NN * NN;          // [8][512]
    unsigned* sp = (unsigned*)(gsp + 8 * NN);  // [T][512][16] words

    const size_t need_main = ((size_t)15 * NN * NN + 8 * NN) * 4
                             + (size_t)T * NN * 16 * 4;

    if (ws_size >= need_main) {
        hipLaunchKernelGGL(gemm_splitk_kernel, dim3(768), dim3(256), 0, stream,
                           x, W, P0, part);
        hipLaunchKernelGGL(combine_kernel, dim3(768), dim3(256), 0, stream,
                           part, bias, M, V0, G);
        hipLaunchKernelGGL(acc0_splitk_kernel, dim3(512), dim3(256), 0, stream,
                           M, V0, G, alpha, ACC0p, gsp);
        hipLaunchKernelGGL(snn_bits9_kernel, dim3(NN), dim3(512), 0, stream,
                           M, G, V0, ACC0p, gsp, alpha, eta, beta, sp, T);
        hipLaunchKernelGGL(expand_kernel, dim3(T * 8), dim3(256), 0, stream,
                           sp, (float*)d_out);
    } else {
        float* Mf  = ws;
        float* V0f = ws + NN * NN;
        float* Gf  = ws + 2 * NN * NN;
        float* gs2 = ws + 3 * NN * NN;
        hipLaunchKernelGGL(gemm64_kernel, dim3(192), dim3(256), 0, stream,
                           x, W, P0, bias, Mf, V0f, Gf);
        hipLaunchKernelGGL(colsum_kernel, dim3(8), dim3(256), 0, stream, Gf, gs2);
        hipLaunchKernelGGL(snn_step_kernel, dim3(256), dim3(256), 0, stream,
                           Mf, Gf, V0f, gs2, alpha, eta, beta, (float*)d_out, T);
    }
}